// Round 14
// baseline (394.920 us; speedup 1.0000x reference)
//
#include <hip/hip_runtime.h>
#include <math.h>

#define B_ 32
#define N_ 8192
#define G_ 128
#define S_ 32
#define ENC_ 384

typedef __attribute__((ext_vector_type(8))) short short8;
typedef __attribute__((ext_vector_type(4))) float f32x4;
typedef __attribute__((ext_vector_type(2))) unsigned u32x2;

__device__ __forceinline__ unsigned short f2bf(float x) {
  unsigned u = __float_as_uint(x);
  u = u + 0x7fffu + ((u >> 16) & 1u);  // RNE
  return (unsigned short)(u >> 16);
}

// packed f32x2 -> bf16x2 (RNE), lo16 = a, hi16 = b
__device__ __forceinline__ unsigned pk_bf16(float a, float b) {
  unsigned r;
  asm("v_cvt_pk_bf16_f32 %0, %1, %2" : "=v"(r) : "v"(a), "v"(b));
  return r;
}

// DPP max step for u64 keys with row_mask; masked-off lanes get old=0 so
// max(k,0)=k (keys always < 2^63: value field is a finite positive float).
template <int CTRL, int RM>
__device__ __forceinline__ unsigned long long dpp_max_rm(unsigned long long k) {
  const int lo = (int)(unsigned)k, hi = (int)(unsigned)(k >> 32);
  const int olo = __builtin_amdgcn_update_dpp(0, lo, CTRL, RM, 0xF, true);
  const int ohi = __builtin_amdgcn_update_dpp(0, hi, CTRL, RM, 0xF, true);
  const unsigned long long o =
      ((unsigned long long)(unsigned)ohi << 32) | (unsigned)(unsigned)olo;
  return o > k ? o : k;
}

// f32 max-reduce over the 16-lane DPP row via row_ror 8/4/2/1
template <int CTRL>
__device__ __forceinline__ float dpp_fmax(float v) {
  const int x = __builtin_amdgcn_update_dpp(0, __float_as_int(v), CTRL, 0xF, 0xF, true);
  return fmaxf(v, __int_as_float(x));
}
__device__ __forceinline__ float rowmax16(float v) {
  v = dpp_fmax<0x128>(v);  // row_ror:8
  v = dpp_fmax<0x124>(v);  // row_ror:4
  v = dpp_fmax<0x122>(v);  // row_ror:2
  v = dpp_fmax<0x121>(v);  // row_ror:1
  return v;
}

// ============================== FPS ==============================
__global__ __launch_bounds__(256) void fps_kernel(const float* __restrict__ pc,
                                                  int* __restrict__ rep) {
  #pragma clang fp contract(off)
  extern __shared__ char smraw[];
  unsigned long long (*redbuf)[4] = (unsigned long long (*)[4])smraw;  // 2*4*8 B
  float* sx = (float*)(smraw + 64);
  float* sy = sx + N_;
  float* sz = sy + N_;
  const int b = blockIdx.x;
  const float* p = pc + (size_t)b * N_ * 3;
  const int tid = threadIdx.x;
  for (int i = tid; i < N_; i += 256) {
    sx[i] = p[i * 3 + 0];
    sy[i] = p[i * 3 + 1];
    sz[i] = p[i * 3 + 2];
  }
  __syncthreads();
  float X[32], Y[32], Z[32], D[32];
  #pragma unroll
  for (int j = 0; j < 32; ++j) {
    const int idx = tid + j * 256;
    X[j] = sx[idx]; Y[j] = sy[idx]; Z[j] = sz[idx];
    D[j] = INFINITY;
  }
  int last = 0;
  const int lane = tid & 63, wave = tid >> 6;  // 4 waves
  for (int k = 0; k < G_; ++k) {
    if (tid == 0) rep[b * G_ + k] = last;
    const float px = sx[last], py = sy[last], pz = sz[last];
    float bestv = -1.0f;
    int besti = 0;
    #pragma unroll
    for (int j = 0; j < 32; ++j) {
      const float dx = X[j] - px, dy = Y[j] - py, dz = Z[j] - pz;
      float dist = dx * dx;
      dist += dy * dy;
      dist += dz * dz;
      const float dj = fminf(D[j], dist);
      D[j] = dj;
      if (dj > bestv) { bestv = dj; besti = tid + j * 256; }  // ascending idx scan
    }
    // maximize (value, 8191-idx): tie -> smallest index
    unsigned long long key =
        ((unsigned long long)__float_as_uint(bestv) << 32) | (unsigned)(8191 - besti);
    key = dpp_max_rm<0xB1, 0xF>(key);   // quad_perm(1,0,3,2) = xor1
    key = dpp_max_rm<0x4E, 0xF>(key);   // quad_perm(2,3,0,1) = xor2
    key = dpp_max_rm<0x141, 0xF>(key);  // row_half_mirror = xor7
    key = dpp_max_rm<0x140, 0xF>(key);  // row_mirror = xor15 -> 16-lane groups done
    key = dpp_max_rm<0x142, 0xA>(key);  // row_bcast15 into rows 1,3
    key = dpp_max_rm<0x143, 0xC>(key);  // row_bcast31 into rows 2,3 -> row3 = wave max
    const int par = k & 1;
    if (lane == 63) redbuf[par][wave] = key;
    __syncthreads();
    unsigned long long kk = redbuf[par][0];
    #pragma unroll
    for (int w = 1; w < 4; ++w) {
      const unsigned long long o = redbuf[par][w];
      if (o > kk) kk = o;
    }
    last = 8191 - (int)(kk & 0xFFFFFFFFu);
  }
}

// ============================== KNN ==============================
// One block (256 thr) per (b,g). Exact top-32 via radix/histogram select on
// unique 45-bit keys (sortable_d2 << 13 | idx): 4 per-wave histograms,
// early-collect once (keys <= selected bin) <= 128, u32 hot path for
// shifts >= 13. Selection + tie-break bit-identical to lax.top_k.
__global__ __launch_bounds__(256) void knn_kernel(const float* __restrict__ pc,
                                                  const int* __restrict__ rep,
                                                  int* __restrict__ nn) {
  #pragma clang fp contract(off)
  const int bg = blockIdx.x;
  const int b = bg >> 7;
  const float* p = pc + (size_t)b * N_ * 3;
  const int tid = threadIdx.x;
  const int lane = tid & 63, wave = tid >> 6;
  const int ridx = rep[bg];
  const float qx = p[ridx * 3 + 0], qy = p[ridx * 3 + 1], qz = p[ridx * 3 + 2];
  float nq = qx * qx;
  nq += qy * qy;
  nq += qz * qz;
  unsigned ub[32];
  #pragma unroll
  for (int j = 0; j < 32; ++j) {
    const int idx = tid + j * 256;
    const float tx = p[idx * 3 + 0], ty = p[idx * 3 + 1], tz = p[idx * 3 + 2];
    float nt = tx * tx;
    nt += ty * ty;
    nt += tz * tz;
    float dt = qx * tx;
    dt += qy * ty;
    dt += qz * tz;
    const float d2 = (nq + nt) - 2.0f * dt;
    unsigned u = __float_as_uint(d2);
    u = (u & 0x80000000u) ? ~u : (u | 0x80000000u);  // float -> sortable uint
    ub[j] = u;
  }

  __shared__ unsigned hist[4][256];
  __shared__ unsigned wsum[4];
  __shared__ int s_bin, s_cexc, s_hbin, s_cnt;
  __shared__ unsigned long long cand[128];

  unsigned long long curPrefix = 0;
  int need = 32;
  int prevShift = 45;
  int stopShift = 0;
  unsigned long long stopPrefix = 0;
  const int shifts[6] = {37, 29, 21, 13, 5, 0};
  #pragma unroll 1
  for (int pass = 0; pass < 6; ++pass) {
    const int sh = shifts[pass];
    const int width = prevShift - sh;
    const unsigned msk = (1u << width) - 1u;
    #pragma unroll
    for (int w = 0; w < 4; ++w) hist[w][tid] = 0;
    if (pass == 0 && tid == 0) s_cnt = 0;
    __syncthreads();
    if (sh >= 13) {  // u32 hot path: key>>x == ub>>(x-13) for x>=13
      const int shp = prevShift - 13, shd = sh - 13;
      const unsigned pref32 = (unsigned)curPrefix;
      #pragma unroll 1
      for (int j = 0; j < 32; ++j) {
        const unsigned u = ub[j];
        if ((shp >= 32 ? 0u : (u >> shp)) == pref32)
          atomicAdd(&hist[wave][(u >> shd) & msk], 1u);
      }
    } else {
      #pragma unroll 1
      for (int j = 0; j < 32; ++j) {
        const unsigned long long key =
            ((unsigned long long)ub[j] << 13) | (unsigned)(tid + j * 256);
        if ((key >> prevShift) == curPrefix)
          atomicAdd(&hist[wave][(unsigned)(key >> sh) & msk], 1u);
      }
    }
    __syncthreads();
    const unsigned v = hist[0][tid] + hist[1][tid] + hist[2][tid] + hist[3][tid];
    unsigned c = v;
    #pragma unroll
    for (int off = 1; off <= 32; off <<= 1) {
      const unsigned o = __shfl_up(c, (unsigned)off);
      if (lane >= off) c += o;
    }
    if (lane == 63) wsum[wave] = c;
    __syncthreads();
    unsigned pre = 0;
    if (wave > 0) pre += wsum[0];
    if (wave > 1) pre += wsum[1];
    if (wave > 2) pre += wsum[2];
    const unsigned cine = c + pre;
    const unsigned cexc = cine - v;
    if (cexc < (unsigned)need && (unsigned)need <= cine) {
      s_bin = tid;
      s_cexc = (int)cexc;
      s_hbin = (int)v;
    }
    __syncthreads();
    curPrefix = (curPrefix << width) | (unsigned)s_bin;
    need -= s_cexc;  // rank within selected bin
    prevShift = sh;
    // keys <= selected bin (global) = (32 - need) below-bin + hbin in-bin
    if ((32 - need) + s_hbin <= 128) {
      stopShift = sh;
      stopPrefix = curPrefix;
      break;
    }
  }
  // collect all keys with (key >> stopShift) <= stopPrefix (count <= 128)
  if (stopShift >= 13) {
    const int shd = stopShift - 13;
    const unsigned pref32 = (unsigned)stopPrefix;
    #pragma unroll 1
    for (int j = 0; j < 32; ++j) {
      if ((ub[j] >> shd) <= pref32) {
        const int pos = atomicAdd(&s_cnt, 1);
        cand[pos] = ((unsigned long long)ub[j] << 13) | (unsigned)(tid + j * 256);
      }
    }
  } else {
    #pragma unroll 1
    for (int j = 0; j < 32; ++j) {
      const unsigned long long key =
          ((unsigned long long)ub[j] << 13) | (unsigned)(tid + j * 256);
      if ((key >> stopShift) <= stopPrefix) {
        const int pos = atomicAdd(&s_cnt, 1);
        cand[pos] = key;
      }
    }
  }
  __syncthreads();
  const int cnt = s_cnt;
  if (tid < cnt) {
    const unsigned long long kt = cand[tid];
    int rank = 0;
    #pragma unroll 1
    for (int j = 0; j < cnt; ++j) rank += (cand[j] < kt) ? 1 : 0;
    if (rank < 32) nn[bg * S_ + rank] = (int)(kt & 8191u);
  }
}

// ==================== LAPACK-faithful 3x3 eigh ====================
__device__ __forceinline__ double slapy2d(double x, double y) {
  return sqrt(x * x + y * y);
}

__device__ void slartg_(double f, double g, double& c, double& s, double& r) {
  if (g == 0.0) { c = 1.0; s = 0.0; r = f; }
  else if (f == 0.0) { c = 0.0; s = copysign(1.0, g); r = fabs(g); }
  else {
    const double d = sqrt(f * f + g * g);
    c = fabs(f) / d;
    r = copysign(d, f);
    s = g / r;
  }
}

__device__ void slaev2_(double a, double b, double c, double& rt1, double& rt2,
                        double& cs1, double& sn1) {
  const double sm = a + c, df = a - c;
  const double adf = fabs(df), tb = b + b, ab = fabs(tb);
  double acmx, acmn;
  if (fabs(a) > fabs(c)) { acmx = a; acmn = c; } else { acmx = c; acmn = a; }
  double rt;
  if (adf > ab) rt = adf * sqrt(1.0 + (ab / adf) * (ab / adf));
  else if (adf < ab) rt = ab * sqrt(1.0 + (adf / ab) * (adf / ab));
  else rt = ab * sqrt(2.0);
  int sgn1;
  if (sm < 0.0) { rt1 = 0.5 * (sm - rt); sgn1 = -1; rt2 = (acmx / rt1) * acmn - (b / rt1) * b; }
  else if (sm > 0.0) { rt1 = 0.5 * (sm + rt); sgn1 = 1; rt2 = (acmx / rt1) * acmn - (b / rt1) * b; }
  else { rt1 = 0.5 * rt; rt2 = -0.5 * rt; sgn1 = 1; }
  double cs;
  int sgn2;
  if (df >= 0.0) { cs = df + rt; sgn2 = 1; } else { cs = df - rt; sgn2 = -1; }
  const double acs = fabs(cs);
  if (acs > ab) {
    const double ct = -tb / cs;
    sn1 = 1.0 / sqrt(1.0 + ct * ct);
    cs1 = ct * sn1;
  } else {
    if (ab == 0.0) { cs1 = 1.0; sn1 = 0.0; }
    else {
      const double tn = -cs / tb;
      cs1 = 1.0 / sqrt(1.0 + tn * tn);
      sn1 = tn * cs1;
    }
  }
  if (sgn1 == sgn2) { const double tn = cs1; cs1 = -sn1; sn1 = tn; }
}

__device__ void eigh33_lapack(const double A[3][3], double dout[3], double Zo[3][3]) {
  double d[3], e[2];
  double Z[3][3];
  {
    const double a00 = A[0][0], a10 = A[1][0], a20 = A[2][0];
    const double a11 = A[1][1], a21 = A[2][1], a22 = A[2][2];
    if (fabs(a20) == 0.0) {
      d[0] = a00; d[1] = a11; d[2] = a22; e[0] = a10; e[1] = a21;
      Z[0][0] = 1; Z[0][1] = 0; Z[0][2] = 0;
      Z[1][0] = 0; Z[1][1] = 1; Z[1][2] = 0;
      Z[2][0] = 0; Z[2][1] = 0; Z[2][2] = 1;
    } else {
      const double beta = -copysign(slapy2d(a10, a20), a10);
      const double tau = (beta - a10) / beta;
      const double v2 = a20 / (a10 - beta);
      const double h11 = 1.0 - tau;
      const double h12 = -tau * v2;
      const double h22 = 1.0 - tau * v2 * v2;
      const double m10 = h11 * a10 + h12 * a20;
      const double m11 = h11 * a11 + h12 * a21;
      const double m12 = h11 * a21 + h12 * a22;
      const double m21 = h12 * a11 + h22 * a21;
      const double m22 = h12 * a21 + h22 * a22;
      d[0] = a00;
      d[1] = m11 * h11 + m12 * h12;
      d[2] = m21 * h12 + m22 * h22;
      e[0] = m10;
      e[1] = m21 * h11 + m22 * h12;
      Z[0][0] = 1; Z[0][1] = 0;   Z[0][2] = 0;
      Z[1][0] = 0; Z[1][1] = h11; Z[1][2] = h12;
      Z[2][0] = 0; Z[2][1] = h12; Z[2][2] = h22;
    }
  }
  const double eps = 5.9604644775390625e-08;
  const double eps2 = eps * eps;
  const double safmin = 1.1754943508222875e-38;
  int jtot = 0;
  const int nmaxit = 90;
  int l1 = 0;
  while (l1 <= 2) {
    if (l1 > 0) e[l1 - 1] = 0.0;
    int m;
    for (m = l1; m <= 1; ++m) {
      const double tst = fabs(e[m]);
      if (tst == 0.0) break;
      if (tst <= (sqrt(fabs(d[m])) * sqrt(fabs(d[m + 1]))) * eps) { e[m] = 0.0; break; }
    }
    int l = l1;
    const int lsv = l;
    int lend = m;
    const int lendsv = lend;
    l1 = m + 1;
    if (lend == l) continue;
    if (fabs(d[lend]) < fabs(d[l])) { lend = lsv; l = lendsv; }
    if (lend > l) {
      for (;;) {
        int mq;
        for (mq = l; mq <= lend - 1; ++mq) {
          const double tst = e[mq] * e[mq];
          if (tst <= (eps2 * fabs(d[mq])) * fabs(d[mq + 1]) + safmin) break;
        }
        if (mq < lend) e[mq] = 0.0;
        double p = d[l];
        if (mq == l) { d[l] = p; l = l + 1; if (l <= lend) continue; break; }
        if (mq == l + 1) {
          double rt1, rt2, c, s;
          slaev2_(d[l], e[l], d[l + 1], rt1, rt2, c, s);
          for (int i = 0; i < 3; ++i) {
            const double t1 = Z[i][l + 1], t0 = Z[i][l];
            Z[i][l + 1] = c * t1 - s * t0;
            Z[i][l] = s * t1 + c * t0;
          }
          d[l] = rt1; d[l + 1] = rt2; e[l] = 0.0;
          l += 2;
          if (l <= lend) continue;
          break;
        }
        if (jtot == nmaxit) break;
        ++jtot;
        double g = (d[l + 1] - p) / (2.0 * e[l]);
        double r = slapy2d(g, 1.0);
        g = d[mq] - p + e[l] / (g + copysign(r, g));
        double s = 1.0, c = 1.0;
        p = 0.0;
        double csv[2], ssv[2];
        for (int i = mq - 1; i >= l; --i) {
          const double f = s * e[i];
          const double bb = c * e[i];
          slartg_(g, f, c, s, r);
          if (i != mq - 1) e[i + 1] = r;
          g = d[i + 1] - p;
          r = (d[i] - g) * s + 2.0 * c * bb;
          p = s * r;
          d[i + 1] = g + p;
          g = c * r - bb;
          csv[i] = c; ssv[i] = -s;
        }
        const int mm = mq - l + 1;
        for (int j = mm - 2; j >= 0; --j) {
          const double ct = csv[l + j], st = ssv[l + j];
          for (int i = 0; i < 3; ++i) {
            const double t1 = Z[i][l + j + 1];
            Z[i][l + j + 1] = ct * t1 - st * Z[i][l + j];
            Z[i][l + j] = st * t1 + ct * Z[i][l + j];
          }
        }
        d[l] = d[l] - p;
        e[l] = g;
      }
    } else {
      for (;;) {
        int mq;
        for (mq = l; mq >= lend + 1; --mq) {
          const double tst = e[mq - 1] * e[mq - 1];
          if (tst <= (eps2 * fabs(d[mq])) * fabs(d[mq - 1]) + safmin) break;
        }
        if (mq > lend) e[mq - 1] = 0.0;
        double p = d[l];
        if (mq == l) { d[l] = p; l = l - 1; if (l >= lend) continue; break; }
        if (mq == l - 1) {
          double rt1, rt2, c, s;
          slaev2_(d[l - 1], e[l - 1], d[l], rt1, rt2, c, s);
          for (int i = 0; i < 3; ++i) {
            const double t1 = Z[i][l], t0 = Z[i][l - 1];
            Z[i][l] = c * t1 - s * t0;
            Z[i][l - 1] = s * t1 + c * t0;
          }
          d[l - 1] = rt1; d[l] = rt2; e[l - 1] = 0.0;
          l -= 2;
          if (l >= lend) continue;
          break;
        }
        if (jtot == nmaxit) break;
        ++jtot;
        double g = (d[l - 1] - p) / (2.0 * e[l - 1]);
        double r = slapy2d(g, 1.0);
        g = d[mq] - p + e[l - 1] / (g + copysign(r, g));
        double s = 1.0, c = 1.0;
        p = 0.0;
        double csv[2], ssv[2];
        for (int i = mq; i <= l - 1; ++i) {
          const double f = s * e[i];
          const double bb = c * e[i];
          slartg_(g, f, c, s, r);
          if (i != mq) e[i - 1] = r;
          g = d[i] - p;
          r = (d[i + 1] - g) * s + 2.0 * c * bb;
          p = s * r;
          d[i] = g + p;
          g = c * r - bb;
          csv[i] = c; ssv[i] = s;
        }
        const int mm = l - mq + 1;
        for (int j = 0; j <= mm - 2; ++j) {
          const double ct = csv[mq + j], st = ssv[mq + j];
          for (int i = 0; i < 3; ++i) {
            const double t1 = Z[i][mq + j + 1];
            Z[i][mq + j + 1] = ct * t1 - st * Z[i][mq + j];
            Z[i][mq + j] = st * t1 + ct * Z[i][mq + j];
          }
        }
        d[l] = d[l] - p;
        e[l - 1] = g;
      }
    }
  }
  for (int ii = 1; ii < 3; ++ii) {
    const int i = ii - 1;
    int k = i;
    double p = d[i];
    for (int j = ii; j < 3; ++j)
      if (d[j] < p) { k = j; p = d[j]; }
    if (k != i) {
      d[k] = d[i];
      d[i] = p;
      for (int q = 0; q < 3; ++q) {
        const double t = Z[q][i];
        Z[q][i] = Z[q][k];
        Z[q][k] = t;
      }
    }
  }
  dout[0] = d[0]; dout[1] = d[1]; dout[2] = d[2];
  for (int i = 0; i < 3; ++i)
    for (int j = 0; j < 3; ++j) Zo[i][j] = Z[i][j];
}

// ============================== LRF ==============================
__global__ __launch_bounds__(64) void lrf_kernel(const float* __restrict__ pc,
                                                 const int* __restrict__ rep,
                                                 const int* __restrict__ nn,
                                                 float* __restrict__ rot) {
  #pragma clang fp contract(off)
  const int bg = blockIdx.x;
  const int b = bg >> 7;
  const float* p = pc + (size_t)b * N_ * 3;
  const int lane = threadIdx.x;
  const int s = lane & 31;
  const int ridx = rep[bg];
  const float cx = p[ridx * 3 + 0], cy = p[ridx * 3 + 1], cz = p[ridx * 3 + 2];
  const int idx = nn[bg * S_ + s];
  const float nx = p[idx * 3 + 0] - cx;
  const float ny = p[idx * 3 + 1] - cy;
  const float nz = p[idx * 3 + 2] - cz;
  float nrm2 = nx * nx;
  nrm2 += ny * ny;
  nrm2 += nz * nz;
  const float nrm = sqrtf(nrm2);
  float wmax = nrm;
  #pragma unroll
  for (int off = 16; off >= 1; off >>= 1) wmax = fmaxf(wmax, __shfl_xor(wmax, off));
  float w = wmax - nrm;
  float wsum = w;
  #pragma unroll
  for (int off = 16; off >= 1; off >>= 1) wsum += __shfl_xor(wsum, off);
  w = w / (wsum + 1e-6f);
  const float spx = 100.0f * nx, spy = 100.0f * ny, spz = 100.0f * nz;
  const float wx = w * spx, wy = w * spy, wz = w * spz;
  float c00 = wx * spx, c01 = wx * spy, c02 = wx * spz;
  float c11 = wy * spy, c12 = wy * spz, c22 = wz * spz;
  #pragma unroll
  for (int off = 16; off >= 1; off >>= 1) {
    c00 += __shfl_xor(c00, off); c01 += __shfl_xor(c01, off); c02 += __shfl_xor(c02, off);
    c11 += __shfl_xor(c11, off); c12 += __shfl_xor(c12, off); c22 += __shfl_xor(c22, off);
  }
  double A[3][3] = {{(double)c00, (double)c01, (double)c02},
                    {(double)c01, (double)c11, (double)c12},
                    {(double)c02, (double)c12, (double)c22}};
  double lam[3], Zm[3][3];
  eigh33_lapack(A, lam, Zm);
  float zx = (float)Zm[0][0], zy = (float)Zm[1][0], zz = (float)Zm[2][0];
  float xx = (float)Zm[0][2], xy = (float)Zm[1][2], xz = (float)Zm[2][2];
  float pj = zx * nx;
  pj += zy * ny;
  pj += zz * nz;
  int npos = __popcll(__ballot(pj > 0.0f) & 0xFFFFFFFFull);
  if (npos < 16) { zx = -zx; zy = -zy; zz = -zz; }
  pj = xx * nx;
  pj += xy * ny;
  pj += xz * nz;
  npos = __popcll(__ballot(pj > 0.0f) & 0xFFFFFFFFull);
  if (npos < 16) { xx = -xx; xy = -xy; xz = -xz; }
  const float yx = zy * xz - zz * xy;
  const float yy = zz * xx - zx * xz;
  const float yz = zx * xy - zy * xx;
  if (lane < 32) {
    float r0 = nx * zx; r0 += ny * zy; r0 += nz * zz;
    float r1 = nx * yx; r1 += ny * yy; r1 += nz * yz;
    float r2 = nx * xx; r2 += ny * xy; r2 += nz * xz;
    const size_t base = (size_t)(bg * S_ + s) * 3;
    rot[base + 0] = r0;
    rot[base + 1] = r1;
    rot[base + 2] = r2;
  }
}

// ==================== weight pre-tiling (f32 -> bf16, MFMA-tiled) ====================
// tiled[nt][kt][lane][j] = W[nt*16 + (lane&15)][ktbase + kt*32 + (lane>>4)*8 + j]
#define P2_ 4096    // 16*4*64
#define P3_ 16384   // 32*8*64
#define P4_ 24576   // 24*16*64
__global__ __launch_bounds__(256) void convw_kernel(
    const float* __restrict__ W2, const float* __restrict__ W3,
    const float* __restrict__ W4, short* __restrict__ w2t,
    short* __restrict__ w3gt, short* __restrict__ w3ft,
    short* __restrict__ w4t) {
  int t = blockIdx.x * 256 + threadIdx.x;
  const float* src;
  short* dst;
  if (t < P2_) {
    const int lane = t & 63, kt = (t >> 6) & 3, nt = t >> 8;
    src = W2 + (nt * 16 + (lane & 15)) * 128 + kt * 32 + ((lane >> 4) << 3);
    dst = w2t + t * 8;
  } else if (t < P2_ + P3_) {
    const int p = t - P2_;
    const int lane = p & 63, kt = (p >> 6) & 7, nt = p >> 9;
    src = W3 + (nt * 16 + (lane & 15)) * 512 + kt * 32 + ((lane >> 4) << 3);
    dst = w3gt + p * 8;
  } else if (t < P2_ + 2 * P3_) {
    const int p = t - P2_ - P3_;
    const int lane = p & 63, kt = (p >> 6) & 7, nt = p >> 9;
    src = W3 + (nt * 16 + (lane & 15)) * 512 + 256 + kt * 32 + ((lane >> 4) << 3);
    dst = w3ft + p * 8;
  } else if (t < P2_ + 2 * P3_ + P4_) {
    const int p = t - P2_ - 2 * P3_;
    const int lane = p & 63, kt = (p >> 6) & 15, nt = p >> 10;
    src = W4 + (nt * 16 + (lane & 15)) * 512 + kt * 32 + ((lane >> 4) << 3);
    dst = w4t + p * 8;
  } else {
    return;
  }
  short8 v;
  #pragma unroll
  for (int j = 0; j < 8; ++j) v[j] = (short)f2bf(src[j]);
  *(short8*)dst = v;
}

// ============================== fused MFMA MLP ==============================
// One block = 512 thr (8 waves) = 2 groups (64 s rows). Operand-swapped MFMA.
// LDS cut 78.6K -> 53.0K for 3 blocks/CU (24 waves): FGA compacted to its 2
// real rows (lanes l15>=2 feed zero B-fragments to the FG MFMA — rows 2-15
// were memset zeros before), SROT aliases FGA (disjoint lifetimes), and
// L3+L4 phased over n3-QUARTERS (f3 buffer 16K). Weights still read exactly
// once per block; K-accumulation order unchanged (bit-identical output).
// kt loops `#pragma unroll 1`; no min-waves cap.
#define OFF_A3   0        // f2 [64][512B] bf16 (32768 B)
#define OFF_R1   32768    // f1 [64][256B] (16 KB) then per-phase f3q [64][256B] (16 KB)
#define OFF_FGA  49152    // fg A-tile rows 0-1 [2][512B] (1024 B); SROT aliases
#define OFF_SROT 49152    // rot [64][3] f32 (768 B) — dead before FGA written
#define OFF_BASE 50176    // base [2][512] f32 (4096 B)
#define LDS_MLP  54272    // 53.0 KB -> 3 blocks/CU

__device__ __forceinline__ int swz(int row, int byteoff) {
  return byteoff ^ ((row & 7) << 4);
}

__global__ __launch_bounds__(512) void mlp_kernel(
    const float* __restrict__ rot,
    const float* __restrict__ W1, const float* __restrict__ b1,
    const float* __restrict__ g1, const float* __restrict__ be1,
    const float* __restrict__ b2, const float* __restrict__ b3,
    const float* __restrict__ g2, const float* __restrict__ be2,
    const float* __restrict__ b4,
    const short* __restrict__ w2t, const short* __restrict__ w3gt,
    const short* __restrict__ w3ft, const short* __restrict__ w4t,
    float* __restrict__ out) {
  extern __shared__ char sm[];
  const int tid = threadIdx.x;
  const int lane = tid & 63, wave = tid >> 6;
  const int l15 = lane & 15, lq = lane >> 4;
  const int bg0 = blockIdx.x * 2;
  const float inv_s = 1.0f / sqrtf(1.0f + 1e-5f);

  // ---- phase 0: stage rot ----
  if (tid < 192) ((float*)(sm + OFF_SROT))[tid] = rot[(size_t)bg0 * 96 + tid];
  __syncthreads();

  // ---- L1: rot[64x3] x W1^T -> relu(bn) -> f1 [64 s][128 k] bf16 ----
  {
    const int o2 = (tid & 63) * 2;   // k pair
    const int rbase = tid >> 6;      // 0..7
    const float w00 = W1[o2 * 3], w01 = W1[o2 * 3 + 1], w02 = W1[o2 * 3 + 2];
    const float w10 = W1[o2 * 3 + 3], w11 = W1[o2 * 3 + 4], w12 = W1[o2 * 3 + 5];
    const float b10 = b1[o2], b11 = b1[o2 + 1];
    const float sc0 = g1[o2] * inv_s, sc1 = g1[o2 + 1] * inv_s;
    const float sh0 = be1[o2], sh1 = be1[o2 + 1];
    const float* sr = (const float*)(sm + OFF_SROT);
    #pragma unroll
    for (int t = 0; t < 8; ++t) {
      const int row = rbase + t * 8;
      const float x = sr[row * 3], y = sr[row * 3 + 1], z = sr[row * 3 + 2];
      const float v0 = fmaxf((x * w00 + y * w01 + z * w02 + b10) * sc0 + sh0, 0.0f);
      const float v1 = fmaxf((x * w10 + y * w11 + z * w12 + b11) * sc1 + sh1, 0.0f);
      *(unsigned*)(sm + OFF_R1 + swz(row, row * 256 + o2 * 2)) = pk_bf16(v0, v1);
    }
  }
  __syncthreads();

  // ---- L2: f2 = W2·f1ᵀ (+b2); fg = per-group colmax over s ----
  {
    f32x4 acc[2][4];
    #pragma unroll
    for (int j = 0; j < 2; ++j)
      #pragma unroll
      for (int st = 0; st < 4; ++st) acc[j][st] = (f32x4){0.f, 0.f, 0.f, 0.f};
    #pragma unroll 1
    for (int kt = 0; kt < 4; ++kt) {
      short8 bf[4];
      #pragma unroll
      for (int st = 0; st < 4; ++st) {
        const int s = st * 16 + l15;
        bf[st] = *(const short8*)(sm + OFF_R1 + swz(s, s * 256 + kt * 64 + (lq << 4)));
      }
      #pragma unroll
      for (int j = 0; j < 2; ++j) {
        const short8 wa = *(const short8*)(w2t + (((wave * 2 + j) * 4 + kt) * 64 + lane) * 8);
        #pragma unroll
        for (int st = 0; st < 4; ++st)
          acc[j][st] = __builtin_amdgcn_mfma_f32_16x16x32_bf16(wa, bf[st], acc[j][st], 0, 0, 0);
      }
    }
    #pragma unroll
    for (int j = 0; j < 2; ++j) {
      const int n0 = (wave * 2 + j) * 16 + (lq << 2);
      const f32x4 b2v = *(const f32x4*)(b2 + n0);
      float vv[4][4];
      #pragma unroll
      for (int st = 0; st < 4; ++st) {
        #pragma unroll
        for (int r = 0; r < 4; ++r) vv[st][r] = acc[j][st][r] + b2v[r];
        const int s = st * 16 + l15;
        const unsigned lo = pk_bf16(vv[st][0], vv[st][1]);
        const unsigned hi = pk_bf16(vv[st][2], vv[st][3]);
        *(u32x2*)(sm + OFF_A3 + swz(s, s * 512 + n0 * 2)) = (u32x2){lo, hi};
      }
      float fg0[4], fg1[4];
      #pragma unroll
      for (int r = 0; r < 4; ++r) {
        fg0[r] = rowmax16(fmaxf(vv[0][r], vv[1][r]));
        fg1[r] = rowmax16(fmaxf(vv[2][r], vv[3][r]));
      }
      if (l15 == 0) {
        *(u32x2*)(sm + OFF_FGA + swz(0, n0 * 2)) =
            (u32x2){pk_bf16(fg0[0], fg0[1]), pk_bf16(fg0[2], fg0[3])};
      } else if (l15 == 1) {
        *(u32x2*)(sm + OFF_FGA + swz(1, 512 + n0 * 2)) =
            (u32x2){pk_bf16(fg1[0], fg1[1]), pk_bf16(fg1[2], fg1[3])};
      }
    }
  }
  __syncthreads();

  // ---- FG: base[g][512] = W3g·fgᵀ (+b3), cols g=0,1 (cols 2-15 zero) ----
  {
    f32x4 acg[4];
    #pragma unroll
    for (int q = 0; q < 4; ++q) acg[q] = (f32x4){0.f, 0.f, 0.f, 0.f};
    #pragma unroll 1
    for (int kt = 0; kt < 8; ++kt) {
      short8 bf = (short8){0, 0, 0, 0, 0, 0, 0, 0};
      if (l15 < 2)
        bf = *(const short8*)(sm + OFF_FGA + swz(l15, l15 * 512 + kt * 64 + (lq << 4)));
      #pragma unroll
      for (int q = 0; q < 4; ++q) {
        const short8 wa = *(const short8*)(w3gt + (((wave * 4 + q) * 8 + kt) * 64 + lane) * 8);
        acg[q] = __builtin_amdgcn_mfma_f32_16x16x32_bf16(wa, bf, acg[q], 0, 0, 0);
      }
    }
    if (l15 < 2) {
      #pragma unroll
      for (int q = 0; q < 4; ++q) {
        const int n3 = (wave * 4 + q) * 16 + (lq << 2);
        const f32x4 b3v = *(const f32x4*)(b3 + n3);
        *(f32x4*)(sm + OFF_BASE + l15 * 2048 + n3 * 4) = acg[q] + b3v;
      }
    }
  }
  __syncthreads();

  // ---- L3 + L4, phased over n3-QUARTERS; weights read once per block. ----
  f32x4 acc4[3][4];  // L4 accumulators, live across phases (48 VGPR)
  #pragma unroll
  for (int q = 0; q < 3; ++q)
    #pragma unroll
    for (int st = 0; st < 4; ++st) acc4[q][st] = (f32x4){0.f, 0.f, 0.f, 0.f};

  #pragma unroll 1
  for (int p = 0; p < 4; ++p) {
    // L3: f3q[64 s][128 n3-cols of quarter p] = relu(bn(base + W3f·f2ᵀ))
    {
      f32x4 ac[4];
      #pragma unroll
      for (int st = 0; st < 4; ++st) ac[st] = (f32x4){0.f, 0.f, 0.f, 0.f};
      #pragma unroll 1
      for (int kt = 0; kt < 8; ++kt) {
        short8 bf[4];
        #pragma unroll
        for (int st = 0; st < 4; ++st) {
          const int s = st * 16 + l15;
          bf[st] = *(const short8*)(sm + OFF_A3 + swz(s, s * 512 + kt * 64 + (lq << 4)));
        }
        const int mt = p * 8 + wave;  // w3ft tile 0..31
        const short8 wa = *(const short8*)(w3ft + ((mt * 8 + kt) * 64 + lane) * 8);
        #pragma unroll
        for (int st = 0; st < 4; ++st)
          ac[st] = __builtin_amdgcn_mfma_f32_16x16x32_bf16(wa, bf[st], ac[st], 0, 0, 0);
      }
      const int ng = (p * 8 + wave) * 16 + (lq << 2);  // global n3
      const int nl = wave * 16 + (lq << 2);            // col within quarter
      f32x4 scv = *(const f32x4*)(g2 + ng);
      const f32x4 shv = *(const f32x4*)(be2 + ng);
      #pragma unroll
      for (int r = 0; r < 4; ++r) scv[r] *= inv_s;
      #pragma unroll
      for (int st = 0; st < 4; ++st) {
        const int g = st >> 1;
        const f32x4 bsv = *(const f32x4*)(sm + OFF_BASE + g * 2048 + ng * 4);
        float v[4];
        #pragma unroll
        for (int r = 0; r < 4; ++r)
          v[r] = fmaxf((ac[st][r] + bsv[r]) * scv[r] + shv[r], 0.0f);
        const int s = st * 16 + l15;
        *(u32x2*)(sm + OFF_R1 + swz(s, s * 256 + nl * 2)) =
            (u32x2){pk_bf16(v[0], v[1]), pk_bf16(v[2], v[3])};
      }
    }
    __syncthreads();
    // L4: accumulate K-quarter p (global kt = p*4 + ktl), all 64 rows
    #pragma unroll 1
    for (int ktl = 0; ktl < 4; ++ktl) {
      short8 bf[4];
      #pragma unroll
      for (int st = 0; st < 4; ++st) {
        const int s = st * 16 + l15;
        bf[st] = *(const short8*)(sm + OFF_R1 + swz(s, s * 256 + ktl * 64 + (lq << 4)));
      }
      #pragma unroll
      for (int q = 0; q < 3; ++q) {
        const short8 wa =
            *(const short8*)(w4t + ((((wave * 3 + q) * 16) + p * 4 + ktl) * 64 + lane) * 8);
        #pragma unroll
        for (int st = 0; st < 4; ++st)
          acc4[q][st] = __builtin_amdgcn_mfma_f32_16x16x32_bf16(wa, bf[st], acc4[q][st], 0, 0, 0);
      }
    }
    __syncthreads();
  }

  // ---- out: per-group colmax over s, +b4 ----
  #pragma unroll
  for (int q = 0; q < 3; ++q) {
    const int n4 = (wave * 3 + q) * 16 + (lq << 2);
    const f32x4 b4v = *(const f32x4*)(b4 + n4);
    float m0[4], m1[4];
    #pragma unroll
    for (int r = 0; r < 4; ++r) {
      m0[r] = rowmax16(fmaxf(acc4[q][0][r], acc4[q][1][r]));
      m1[r] = rowmax16(fmaxf(acc4[q][2][r], acc4[q][3][r]));
    }
    if (l15 == 0) {
      f32x4 o;
      #pragma unroll
      for (int r = 0; r < 4; ++r) o[r] = m0[r] + b4v[r];
      *(f32x4*)(out + (size_t)bg0 * ENC_ + n4) = o;
    } else if (l15 == 1) {
      f32x4 o;
      #pragma unroll
      for (int r = 0; r < 4; ++r) o[r] = m1[r] + b4v[r];
      *(f32x4*)(out + (size_t)(bg0 + 1) * ENC_ + n4) = o;
    }
  }
}

// ============================== launch ==============================
extern "C" void kernel_launch(void* const* d_in, const int* in_sizes, int n_in,
                              void* d_out, int out_size, void* d_ws, size_t ws_size,
                              hipStream_t stream) {
  const float* pc  = (const float*)d_in[0];
  const float* W1  = (const float*)d_in[1];
  const float* b1  = (const float*)d_in[2];
  const float* g1  = (const float*)d_in[3];
  const float* be1 = (const float*)d_in[4];
  const float* W2  = (const float*)d_in[5];
  const float* b2  = (const float*)d_in[6];
  const float* W3  = (const float*)d_in[7];
  const float* b3  = (const float*)d_in[8];
  const float* g2  = (const float*)d_in[9];
  const float* be2 = (const float*)d_in[10];
  const float* W4  = (const float*)d_in[11];
  const float* b4  = (const float*)d_in[12];
  float* out = (float*)d_out;
  char* ws = (char*)d_ws;
  int* rep    = (int*)ws;                         // 16384 B
  int* nn     = (int*)(ws + 16384);               // 524288 B
  float* rot  = (float*)(ws + 540672);            // 1572864 B
  short* w2t  = (short*)(ws + 2113536);           // 65536 B
  short* w3gt = (short*)(ws + 2179072);           // 262144 B
  short* w3ft = (short*)(ws + 2441216);           // 262144 B
  short* w4t  = (short*)(ws + 2703360);           // 393216 B (ends 3096576)

  const size_t fps_lds = 64 + (size_t)3 * N_ * 4;  // 98368 B

  convw_kernel<<<240, 256, 0, stream>>>(W2, W3, W4, w2t, w3gt, w3ft, w4t);
  fps_kernel<<<B_, 256, fps_lds, stream>>>(pc, rep);
  knn_kernel<<<B_ * G_, 256, 0, stream>>>(pc, rep, nn);
  lrf_kernel<<<B_ * G_, 64, 0, stream>>>(pc, rep, nn, rot);
  mlp_kernel<<<B_ * G_ / 2, 512, LDS_MLP, stream>>>(
      rot, W1, b1, g1, be1, b2, b3, g2, be2, b4, w2t, w3gt, w3ft, w4t, out);
}

// Round 15
// 386.738 us; speedup vs baseline: 1.0212x; 1.0212x over previous
//
#include <hip/hip_runtime.h>
#include <math.h>

#define B_ 32
#define N_ 8192
#define G_ 128
#define S_ 32
#define ENC_ 384

typedef __attribute__((ext_vector_type(8))) short short8;
typedef __attribute__((ext_vector_type(4))) float f32x4;
typedef __attribute__((ext_vector_type(2))) unsigned u32x2;

__device__ __forceinline__ unsigned short f2bf(float x) {
  unsigned u = __float_as_uint(x);
  u = u + 0x7fffu + ((u >> 16) & 1u);  // RNE
  return (unsigned short)(u >> 16);
}

// packed f32x2 -> bf16x2 (RNE), lo16 = a, hi16 = b
__device__ __forceinline__ unsigned pk_bf16(float a, float b) {
  unsigned r;
  asm("v_cvt_pk_bf16_f32 %0, %1, %2" : "=v"(r) : "v"(a), "v"(b));
  return r;
}

// DPP max step for u64 keys with row_mask; masked-off lanes get old=0 so
// max(k,0)=k (keys always < 2^63: value field is a finite positive float).
template <int CTRL, int RM>
__device__ __forceinline__ unsigned long long dpp_max_rm(unsigned long long k) {
  const int lo = (int)(unsigned)k, hi = (int)(unsigned)(k >> 32);
  const int olo = __builtin_amdgcn_update_dpp(0, lo, CTRL, RM, 0xF, true);
  const int ohi = __builtin_amdgcn_update_dpp(0, hi, CTRL, RM, 0xF, true);
  const unsigned long long o =
      ((unsigned long long)(unsigned)ohi << 32) | (unsigned)(unsigned)olo;
  return o > k ? o : k;
}

// f32 max-reduce over the 16-lane DPP row via row_ror 8/4/2/1
template <int CTRL>
__device__ __forceinline__ float dpp_fmax(float v) {
  const int x = __builtin_amdgcn_update_dpp(0, __float_as_int(v), CTRL, 0xF, 0xF, true);
  return fmaxf(v, __int_as_float(x));
}
__device__ __forceinline__ float rowmax16(float v) {
  v = dpp_fmax<0x128>(v);  // row_ror:8
  v = dpp_fmax<0x124>(v);  // row_ror:4
  v = dpp_fmax<0x122>(v);  // row_ror:2
  v = dpp_fmax<0x121>(v);  // row_ror:1
  return v;
}

// ============================== FPS ==============================
__global__ __launch_bounds__(256) void fps_kernel(const float* __restrict__ pc,
                                                  int* __restrict__ rep) {
  #pragma clang fp contract(off)
  extern __shared__ char smraw[];
  unsigned long long (*redbuf)[4] = (unsigned long long (*)[4])smraw;  // 2*4*8 B
  float* sx = (float*)(smraw + 64);
  float* sy = sx + N_;
  float* sz = sy + N_;
  const int b = blockIdx.x;
  const float* p = pc + (size_t)b * N_ * 3;
  const int tid = threadIdx.x;
  for (int i = tid; i < N_; i += 256) {
    sx[i] = p[i * 3 + 0];
    sy[i] = p[i * 3 + 1];
    sz[i] = p[i * 3 + 2];
  }
  __syncthreads();
  float X[32], Y[32], Z[32], D[32];
  #pragma unroll
  for (int j = 0; j < 32; ++j) {
    const int idx = tid + j * 256;
    X[j] = sx[idx]; Y[j] = sy[idx]; Z[j] = sz[idx];
    D[j] = INFINITY;
  }
  int last = 0;
  const int lane = tid & 63, wave = tid >> 6;  // 4 waves
  for (int k = 0; k < G_; ++k) {
    if (tid == 0) rep[b * G_ + k] = last;
    const float px = sx[last], py = sy[last], pz = sz[last];
    float bestv = -1.0f;
    int besti = 0;
    #pragma unroll
    for (int j = 0; j < 32; ++j) {
      const float dx = X[j] - px, dy = Y[j] - py, dz = Z[j] - pz;
      float dist = dx * dx;
      dist += dy * dy;
      dist += dz * dz;
      const float dj = fminf(D[j], dist);
      D[j] = dj;
      if (dj > bestv) { bestv = dj; besti = tid + j * 256; }  // ascending idx scan
    }
    // maximize (value, 8191-idx): tie -> smallest index
    unsigned long long key =
        ((unsigned long long)__float_as_uint(bestv) << 32) | (unsigned)(8191 - besti);
    key = dpp_max_rm<0xB1, 0xF>(key);   // quad_perm(1,0,3,2) = xor1
    key = dpp_max_rm<0x4E, 0xF>(key);   // quad_perm(2,3,0,1) = xor2
    key = dpp_max_rm<0x141, 0xF>(key);  // row_half_mirror = xor7
    key = dpp_max_rm<0x140, 0xF>(key);  // row_mirror = xor15 -> 16-lane groups done
    key = dpp_max_rm<0x142, 0xA>(key);  // row_bcast15 into rows 1,3
    key = dpp_max_rm<0x143, 0xC>(key);  // row_bcast31 into rows 2,3 -> row3 = wave max
    const int par = k & 1;
    if (lane == 63) redbuf[par][wave] = key;
    __syncthreads();
    unsigned long long kk = redbuf[par][0];
    #pragma unroll
    for (int w = 1; w < 4; ++w) {
      const unsigned long long o = redbuf[par][w];
      if (o > kk) kk = o;
    }
    last = 8191 - (int)(kk & 0xFFFFFFFFu);
  }
}

// ============================== KNN ==============================
// One block (256 thr) per (b,g). Exact top-32 via radix/histogram select on
// unique 45-bit keys (sortable_d2 << 13 | idx): 4 per-wave histograms,
// early-collect once (keys <= selected bin) <= 128, u32 hot path for
// shifts >= 13. Selection + tie-break bit-identical to lax.top_k.
__global__ __launch_bounds__(256) void knn_kernel(const float* __restrict__ pc,
                                                  const int* __restrict__ rep,
                                                  int* __restrict__ nn) {
  #pragma clang fp contract(off)
  const int bg = blockIdx.x;
  const int b = bg >> 7;
  const float* p = pc + (size_t)b * N_ * 3;
  const int tid = threadIdx.x;
  const int lane = tid & 63, wave = tid >> 6;
  const int ridx = rep[bg];
  const float qx = p[ridx * 3 + 0], qy = p[ridx * 3 + 1], qz = p[ridx * 3 + 2];
  float nq = qx * qx;
  nq += qy * qy;
  nq += qz * qz;
  unsigned ub[32];
  #pragma unroll
  for (int j = 0; j < 32; ++j) {
    const int idx = tid + j * 256;
    const float tx = p[idx * 3 + 0], ty = p[idx * 3 + 1], tz = p[idx * 3 + 2];
    float nt = tx * tx;
    nt += ty * ty;
    nt += tz * tz;
    float dt = qx * tx;
    dt += qy * ty;
    dt += qz * tz;
    const float d2 = (nq + nt) - 2.0f * dt;
    unsigned u = __float_as_uint(d2);
    u = (u & 0x80000000u) ? ~u : (u | 0x80000000u);  // float -> sortable uint
    ub[j] = u;
  }

  __shared__ unsigned hist[4][256];
  __shared__ unsigned wsum[4];
  __shared__ int s_bin, s_cexc, s_hbin, s_cnt;
  __shared__ unsigned long long cand[128];

  unsigned long long curPrefix = 0;
  int need = 32;
  int prevShift = 45;
  int stopShift = 0;
  unsigned long long stopPrefix = 0;
  const int shifts[6] = {37, 29, 21, 13, 5, 0};
  #pragma unroll 1
  for (int pass = 0; pass < 6; ++pass) {
    const int sh = shifts[pass];
    const int width = prevShift - sh;
    const unsigned msk = (1u << width) - 1u;
    #pragma unroll
    for (int w = 0; w < 4; ++w) hist[w][tid] = 0;
    if (pass == 0 && tid == 0) s_cnt = 0;
    __syncthreads();
    if (sh >= 13) {  // u32 hot path: key>>x == ub>>(x-13) for x>=13
      const int shp = prevShift - 13, shd = sh - 13;
      const unsigned pref32 = (unsigned)curPrefix;
      #pragma unroll 1
      for (int j = 0; j < 32; ++j) {
        const unsigned u = ub[j];
        if ((shp >= 32 ? 0u : (u >> shp)) == pref32)
          atomicAdd(&hist[wave][(u >> shd) & msk], 1u);
      }
    } else {
      #pragma unroll 1
      for (int j = 0; j < 32; ++j) {
        const unsigned long long key =
            ((unsigned long long)ub[j] << 13) | (unsigned)(tid + j * 256);
        if ((key >> prevShift) == curPrefix)
          atomicAdd(&hist[wave][(unsigned)(key >> sh) & msk], 1u);
      }
    }
    __syncthreads();
    const unsigned v = hist[0][tid] + hist[1][tid] + hist[2][tid] + hist[3][tid];
    unsigned c = v;
    #pragma unroll
    for (int off = 1; off <= 32; off <<= 1) {
      const unsigned o = __shfl_up(c, (unsigned)off);
      if (lane >= off) c += o;
    }
    if (lane == 63) wsum[wave] = c;
    __syncthreads();
    unsigned pre = 0;
    if (wave > 0) pre += wsum[0];
    if (wave > 1) pre += wsum[1];
    if (wave > 2) pre += wsum[2];
    const unsigned cine = c + pre;
    const unsigned cexc = cine - v;
    if (cexc < (unsigned)need && (unsigned)need <= cine) {
      s_bin = tid;
      s_cexc = (int)cexc;
      s_hbin = (int)v;
    }
    __syncthreads();
    curPrefix = (curPrefix << width) | (unsigned)s_bin;
    need -= s_cexc;  // rank within selected bin
    prevShift = sh;
    // keys <= selected bin (global) = (32 - need) below-bin + hbin in-bin
    if ((32 - need) + s_hbin <= 128) {
      stopShift = sh;
      stopPrefix = curPrefix;
      break;
    }
  }
  // collect all keys with (key >> stopShift) <= stopPrefix (count <= 128)
  if (stopShift >= 13) {
    const int shd = stopShift - 13;
    const unsigned pref32 = (unsigned)stopPrefix;
    #pragma unroll 1
    for (int j = 0; j < 32; ++j) {
      if ((ub[j] >> shd) <= pref32) {
        const int pos = atomicAdd(&s_cnt, 1);
        cand[pos] = ((unsigned long long)ub[j] << 13) | (unsigned)(tid + j * 256);
      }
    }
  } else {
    #pragma unroll 1
    for (int j = 0; j < 32; ++j) {
      const unsigned long long key =
          ((unsigned long long)ub[j] << 13) | (unsigned)(tid + j * 256);
      if ((key >> stopShift) <= stopPrefix) {
        const int pos = atomicAdd(&s_cnt, 1);
        cand[pos] = key;
      }
    }
  }
  __syncthreads();
  const int cnt = s_cnt;
  if (tid < cnt) {
    const unsigned long long kt = cand[tid];
    int rank = 0;
    #pragma unroll 1
    for (int j = 0; j < cnt; ++j) rank += (cand[j] < kt) ? 1 : 0;
    if (rank < 32) nn[bg * S_ + rank] = (int)(kt & 8191u);
  }
}

// ==================== LAPACK-faithful 3x3 eigh ====================
__device__ __forceinline__ double slapy2d(double x, double y) {
  return sqrt(x * x + y * y);
}

__device__ void slartg_(double f, double g, double& c, double& s, double& r) {
  if (g == 0.0) { c = 1.0; s = 0.0; r = f; }
  else if (f == 0.0) { c = 0.0; s = copysign(1.0, g); r = fabs(g); }
  else {
    const double d = sqrt(f * f + g * g);
    c = fabs(f) / d;
    r = copysign(d, f);
    s = g / r;
  }
}

__device__ void slaev2_(double a, double b, double c, double& rt1, double& rt2,
                        double& cs1, double& sn1) {
  const double sm = a + c, df = a - c;
  const double adf = fabs(df), tb = b + b, ab = fabs(tb);
  double acmx, acmn;
  if (fabs(a) > fabs(c)) { acmx = a; acmn = c; } else { acmx = c; acmn = a; }
  double rt;
  if (adf > ab) rt = adf * sqrt(1.0 + (ab / adf) * (ab / adf));
  else if (adf < ab) rt = ab * sqrt(1.0 + (adf / ab) * (adf / ab));
  else rt = ab * sqrt(2.0);
  int sgn1;
  if (sm < 0.0) { rt1 = 0.5 * (sm - rt); sgn1 = -1; rt2 = (acmx / rt1) * acmn - (b / rt1) * b; }
  else if (sm > 0.0) { rt1 = 0.5 * (sm + rt); sgn1 = 1; rt2 = (acmx / rt1) * acmn - (b / rt1) * b; }
  else { rt1 = 0.5 * rt; rt2 = -0.5 * rt; sgn1 = 1; }
  double cs;
  int sgn2;
  if (df >= 0.0) { cs = df + rt; sgn2 = 1; } else { cs = df - rt; sgn2 = -1; }
  const double acs = fabs(cs);
  if (acs > ab) {
    const double ct = -tb / cs;
    sn1 = 1.0 / sqrt(1.0 + ct * ct);
    cs1 = ct * sn1;
  } else {
    if (ab == 0.0) { cs1 = 1.0; sn1 = 0.0; }
    else {
      const double tn = -cs / tb;
      cs1 = 1.0 / sqrt(1.0 + tn * tn);
      sn1 = tn * cs1;
    }
  }
  if (sgn1 == sgn2) { const double tn = cs1; cs1 = -sn1; sn1 = tn; }
}

__device__ void eigh33_lapack(const double A[3][3], double dout[3], double Zo[3][3]) {
  double d[3], e[2];
  double Z[3][3];
  {
    const double a00 = A[0][0], a10 = A[1][0], a20 = A[2][0];
    const double a11 = A[1][1], a21 = A[2][1], a22 = A[2][2];
    if (fabs(a20) == 0.0) {
      d[0] = a00; d[1] = a11; d[2] = a22; e[0] = a10; e[1] = a21;
      Z[0][0] = 1; Z[0][1] = 0; Z[0][2] = 0;
      Z[1][0] = 0; Z[1][1] = 1; Z[1][2] = 0;
      Z[2][0] = 0; Z[2][1] = 0; Z[2][2] = 1;
    } else {
      const double beta = -copysign(slapy2d(a10, a20), a10);
      const double tau = (beta - a10) / beta;
      const double v2 = a20 / (a10 - beta);
      const double h11 = 1.0 - tau;
      const double h12 = -tau * v2;
      const double h22 = 1.0 - tau * v2 * v2;
      const double m10 = h11 * a10 + h12 * a20;
      const double m11 = h11 * a11 + h12 * a21;
      const double m12 = h11 * a21 + h12 * a22;
      const double m21 = h12 * a11 + h22 * a21;
      const double m22 = h12 * a21 + h22 * a22;
      d[0] = a00;
      d[1] = m11 * h11 + m12 * h12;
      d[2] = m21 * h12 + m22 * h22;
      e[0] = m10;
      e[1] = m21 * h11 + m22 * h12;
      Z[0][0] = 1; Z[0][1] = 0;   Z[0][2] = 0;
      Z[1][0] = 0; Z[1][1] = h11; Z[1][2] = h12;
      Z[2][0] = 0; Z[2][1] = h12; Z[2][2] = h22;
    }
  }
  const double eps = 5.9604644775390625e-08;
  const double eps2 = eps * eps;
  const double safmin = 1.1754943508222875e-38;
  int jtot = 0;
  const int nmaxit = 90;
  int l1 = 0;
  while (l1 <= 2) {
    if (l1 > 0) e[l1 - 1] = 0.0;
    int m;
    for (m = l1; m <= 1; ++m) {
      const double tst = fabs(e[m]);
      if (tst == 0.0) break;
      if (tst <= (sqrt(fabs(d[m])) * sqrt(fabs(d[m + 1]))) * eps) { e[m] = 0.0; break; }
    }
    int l = l1;
    const int lsv = l;
    int lend = m;
    const int lendsv = lend;
    l1 = m + 1;
    if (lend == l) continue;
    if (fabs(d[lend]) < fabs(d[l])) { lend = lsv; l = lendsv; }
    if (lend > l) {
      for (;;) {
        int mq;
        for (mq = l; mq <= lend - 1; ++mq) {
          const double tst = e[mq] * e[mq];
          if (tst <= (eps2 * fabs(d[mq])) * fabs(d[mq + 1]) + safmin) break;
        }
        if (mq < lend) e[mq] = 0.0;
        double p = d[l];
        if (mq == l) { d[l] = p; l = l + 1; if (l <= lend) continue; break; }
        if (mq == l + 1) {
          double rt1, rt2, c, s;
          slaev2_(d[l], e[l], d[l + 1], rt1, rt2, c, s);
          for (int i = 0; i < 3; ++i) {
            const double t1 = Z[i][l + 1], t0 = Z[i][l];
            Z[i][l + 1] = c * t1 - s * t0;
            Z[i][l] = s * t1 + c * t0;
          }
          d[l] = rt1; d[l + 1] = rt2; e[l] = 0.0;
          l += 2;
          if (l <= lend) continue;
          break;
        }
        if (jtot == nmaxit) break;
        ++jtot;
        double g = (d[l + 1] - p) / (2.0 * e[l]);
        double r = slapy2d(g, 1.0);
        g = d[mq] - p + e[l] / (g + copysign(r, g));
        double s = 1.0, c = 1.0;
        p = 0.0;
        double csv[2], ssv[2];
        for (int i = mq - 1; i >= l; --i) {
          const double f = s * e[i];
          const double bb = c * e[i];
          slartg_(g, f, c, s, r);
          if (i != mq - 1) e[i + 1] = r;
          g = d[i + 1] - p;
          r = (d[i] - g) * s + 2.0 * c * bb;
          p = s * r;
          d[i + 1] = g + p;
          g = c * r - bb;
          csv[i] = c; ssv[i] = -s;
        }
        const int mm = mq - l + 1;
        for (int j = mm - 2; j >= 0; --j) {
          const double ct = csv[l + j], st = ssv[l + j];
          for (int i = 0; i < 3; ++i) {
            const double t1 = Z[i][l + j + 1];
            Z[i][l + j + 1] = ct * t1 - st * Z[i][l + j];
            Z[i][l + j] = st * t1 + ct * Z[i][l + j];
          }
        }
        d[l] = d[l] - p;
        e[l] = g;
      }
    } else {
      for (;;) {
        int mq;
        for (mq = l; mq >= lend + 1; --mq) {
          const double tst = e[mq - 1] * e[mq - 1];
          if (tst <= (eps2 * fabs(d[mq])) * fabs(d[mq - 1]) + safmin) break;
        }
        if (mq > lend) e[mq - 1] = 0.0;
        double p = d[l];
        if (mq == l) { d[l] = p; l = l - 1; if (l >= lend) continue; break; }
        if (mq == l - 1) {
          double rt1, rt2, c, s;
          slaev2_(d[l - 1], e[l - 1], d[l], rt1, rt2, c, s);
          for (int i = 0; i < 3; ++i) {
            const double t1 = Z[i][l], t0 = Z[i][l - 1];
            Z[i][l] = c * t1 - s * t0;
            Z[i][l - 1] = s * t1 + c * t0;
          }
          d[l - 1] = rt1; d[l] = rt2; e[l - 1] = 0.0;
          l -= 2;
          if (l >= lend) continue;
          break;
        }
        if (jtot == nmaxit) break;
        ++jtot;
        double g = (d[l - 1] - p) / (2.0 * e[l - 1]);
        double r = slapy2d(g, 1.0);
        g = d[mq] - p + e[l - 1] / (g + copysign(r, g));
        double s = 1.0, c = 1.0;
        p = 0.0;
        double csv[2], ssv[2];
        for (int i = mq; i <= l - 1; ++i) {
          const double f = s * e[i];
          const double bb = c * e[i];
          slartg_(g, f, c, s, r);
          if (i != mq) e[i - 1] = r;
          g = d[i] - p;
          r = (d[i + 1] - g) * s + 2.0 * c * bb;
          p = s * r;
          d[i] = g + p;
          g = c * r - bb;
          csv[i] = c; ssv[i] = s;
        }
        const int mm = l - mq + 1;
        for (int j = 0; j <= mm - 2; ++j) {
          const double ct = csv[mq + j], st = ssv[mq + j];
          for (int i = 0; i < 3; ++i) {
            const double t1 = Z[i][mq + j + 1];
            Z[i][mq + j + 1] = ct * t1 - st * Z[i][mq + j];
            Z[i][mq + j] = st * t1 + ct * Z[i][mq + j];
          }
        }
        d[l] = d[l] - p;
        e[l - 1] = g;
      }
    }
  }
  for (int ii = 1; ii < 3; ++ii) {
    const int i = ii - 1;
    int k = i;
    double p = d[i];
    for (int j = ii; j < 3; ++j)
      if (d[j] < p) { k = j; p = d[j]; }
    if (k != i) {
      d[k] = d[i];
      d[i] = p;
      for (int q = 0; q < 3; ++q) {
        const double t = Z[q][i];
        Z[q][i] = Z[q][k];
        Z[q][k] = t;
      }
    }
  }
  dout[0] = d[0]; dout[1] = d[1]; dout[2] = d[2];
  for (int i = 0; i < 3; ++i)
    for (int j = 0; j < 3; ++j) Zo[i][j] = Z[i][j];
}

// ============================== LRF ==============================
__global__ __launch_bounds__(64) void lrf_kernel(const float* __restrict__ pc,
                                                 const int* __restrict__ rep,
                                                 const int* __restrict__ nn,
                                                 float* __restrict__ rot) {
  #pragma clang fp contract(off)
  const int bg = blockIdx.x;
  const int b = bg >> 7;
  const float* p = pc + (size_t)b * N_ * 3;
  const int lane = threadIdx.x;
  const int s = lane & 31;
  const int ridx = rep[bg];
  const float cx = p[ridx * 3 + 0], cy = p[ridx * 3 + 1], cz = p[ridx * 3 + 2];
  const int idx = nn[bg * S_ + s];
  const float nx = p[idx * 3 + 0] - cx;
  const float ny = p[idx * 3 + 1] - cy;
  const float nz = p[idx * 3 + 2] - cz;
  float nrm2 = nx * nx;
  nrm2 += ny * ny;
  nrm2 += nz * nz;
  const float nrm = sqrtf(nrm2);
  float wmax = nrm;
  #pragma unroll
  for (int off = 16; off >= 1; off >>= 1) wmax = fmaxf(wmax, __shfl_xor(wmax, off));
  float w = wmax - nrm;
  float wsum = w;
  #pragma unroll
  for (int off = 16; off >= 1; off >>= 1) wsum += __shfl_xor(wsum, off);
  w = w / (wsum + 1e-6f);
  const float spx = 100.0f * nx, spy = 100.0f * ny, spz = 100.0f * nz;
  const float wx = w * spx, wy = w * spy, wz = w * spz;
  float c00 = wx * spx, c01 = wx * spy, c02 = wx * spz;
  float c11 = wy * spy, c12 = wy * spz, c22 = wz * spz;
  #pragma unroll
  for (int off = 16; off >= 1; off >>= 1) {
    c00 += __shfl_xor(c00, off); c01 += __shfl_xor(c01, off); c02 += __shfl_xor(c02, off);
    c11 += __shfl_xor(c11, off); c12 += __shfl_xor(c12, off); c22 += __shfl_xor(c22, off);
  }
  double A[3][3] = {{(double)c00, (double)c01, (double)c02},
                    {(double)c01, (double)c11, (double)c12},
                    {(double)c02, (double)c12, (double)c22}};
  double lam[3], Zm[3][3];
  eigh33_lapack(A, lam, Zm);
  float zx = (float)Zm[0][0], zy = (float)Zm[1][0], zz = (float)Zm[2][0];
  float xx = (float)Zm[0][2], xy = (float)Zm[1][2], xz = (float)Zm[2][2];
  float pj = zx * nx;
  pj += zy * ny;
  pj += zz * nz;
  int npos = __popcll(__ballot(pj > 0.0f) & 0xFFFFFFFFull);
  if (npos < 16) { zx = -zx; zy = -zy; zz = -zz; }
  pj = xx * nx;
  pj += xy * ny;
  pj += xz * nz;
  npos = __popcll(__ballot(pj > 0.0f) & 0xFFFFFFFFull);
  if (npos < 16) { xx = -xx; xy = -xy; xz = -xz; }
  const float yx = zy * xz - zz * xy;
  const float yy = zz * xx - zx * xz;
  const float yz = zx * xy - zy * xx;
  if (lane < 32) {
    float r0 = nx * zx; r0 += ny * zy; r0 += nz * zz;
    float r1 = nx * yx; r1 += ny * yy; r1 += nz * yz;
    float r2 = nx * xx; r2 += ny * xy; r2 += nz * xz;
    const size_t base = (size_t)(bg * S_ + s) * 3;
    rot[base + 0] = r0;
    rot[base + 1] = r1;
    rot[base + 2] = r2;
  }
}

// ==================== weight pre-tiling (f32 -> bf16, MFMA-tiled) ====================
// tiled[nt][kt][lane][j] = W[nt*16 + (lane&15)][ktbase + kt*32 + (lane>>4)*8 + j]
#define P2_ 4096    // 16*4*64
#define P3_ 16384   // 32*8*64
#define P4_ 24576   // 24*16*64
__global__ __launch_bounds__(256) void convw_kernel(
    const float* __restrict__ W2, const float* __restrict__ W3,
    const float* __restrict__ W4, short* __restrict__ w2t,
    short* __restrict__ w3gt, short* __restrict__ w3ft,
    short* __restrict__ w4t) {
  int t = blockIdx.x * 256 + threadIdx.x;
  const float* src;
  short* dst;
  if (t < P2_) {
    const int lane = t & 63, kt = (t >> 6) & 3, nt = t >> 8;
    src = W2 + (nt * 16 + (lane & 15)) * 128 + kt * 32 + ((lane >> 4) << 3);
    dst = w2t + t * 8;
  } else if (t < P2_ + P3_) {
    const int p = t - P2_;
    const int lane = p & 63, kt = (p >> 6) & 7, nt = p >> 9;
    src = W3 + (nt * 16 + (lane & 15)) * 512 + kt * 32 + ((lane >> 4) << 3);
    dst = w3gt + p * 8;
  } else if (t < P2_ + 2 * P3_) {
    const int p = t - P2_ - P3_;
    const int lane = p & 63, kt = (p >> 6) & 7, nt = p >> 9;
    src = W3 + (nt * 16 + (lane & 15)) * 512 + 256 + kt * 32 + ((lane >> 4) << 3);
    dst = w3ft + p * 8;
  } else if (t < P2_ + 2 * P3_ + P4_) {
    const int p = t - P2_ - 2 * P3_;
    const int lane = p & 63, kt = (p >> 6) & 15, nt = p >> 10;
    src = W4 + (nt * 16 + (lane & 15)) * 512 + kt * 32 + ((lane >> 4) << 3);
    dst = w4t + p * 8;
  } else {
    return;
  }
  short8 v;
  #pragma unroll
  for (int j = 0; j < 8; ++j) v[j] = (short)f2bf(src[j]);
  *(short8*)dst = v;
}

// ============================== fused MFMA MLP ==============================
// One block = 512 thr (8 waves) = 2 groups (64 s rows). Operand-swapped MFMA.
// R15 = R13 n-halves phasing (best measured: weights read once, 512B f3 rows)
// + R14's verified-free wins: FGA compacted to its 2 real rows (lanes
// l15>=2 feed zero B-fragments — proven bit-identical in R14) and SROT
// aliasing FGA. No memset. LDS 70.7 KB (2 blocks/CU; R14 showed 53 KB does
// NOT yield 3 blocks — occupancy stayed 42% while quartering overhead hurt).
// kt loops `#pragma unroll 1`; no min-waves cap.
#define OFF_A3   0        // f2 [64][512B] bf16 (32768 B)
#define OFF_R1   32768    // f1 [64][256B] (16 KB) then per-phase f3 [64][512B] (32 KB)
#define OFF_FGA  65536    // fg A-tile rows 0-1 [2][512B] (1024 B); SROT aliases
#define OFF_SROT 65536    // rot [64][3] f32 (768 B) — dead before FGA written
#define OFF_BASE 66560    // base [2][512] f32 (4096 B)
#define LDS_MLP  70656    // 69 KB -> 2 blocks/CU

__device__ __forceinline__ int swz(int row, int byteoff) {
  return byteoff ^ ((row & 7) << 4);
}

__global__ __launch_bounds__(512) void mlp_kernel(
    const float* __restrict__ rot,
    const float* __restrict__ W1, const float* __restrict__ b1,
    const float* __restrict__ g1, const float* __restrict__ be1,
    const float* __restrict__ b2, const float* __restrict__ b3,
    const float* __restrict__ g2, const float* __restrict__ be2,
    const float* __restrict__ b4,
    const short* __restrict__ w2t, const short* __restrict__ w3gt,
    const short* __restrict__ w3ft, const short* __restrict__ w4t,
    float* __restrict__ out) {
  extern __shared__ char sm[];
  const int tid = threadIdx.x;
  const int lane = tid & 63, wave = tid >> 6;
  const int l15 = lane & 15, lq = lane >> 4;
  const int bg0 = blockIdx.x * 2;
  const float inv_s = 1.0f / sqrtf(1.0f + 1e-5f);

  // ---- phase 0: stage rot ----
  if (tid < 192) ((float*)(sm + OFF_SROT))[tid] = rot[(size_t)bg0 * 96 + tid];
  __syncthreads();

  // ---- L1: rot[64x3] x W1^T -> relu(bn) -> f1 [64 s][128 k] bf16 ----
  {
    const int o2 = (tid & 63) * 2;   // k pair
    const int rbase = tid >> 6;      // 0..7
    const float w00 = W1[o2 * 3], w01 = W1[o2 * 3 + 1], w02 = W1[o2 * 3 + 2];
    const float w10 = W1[o2 * 3 + 3], w11 = W1[o2 * 3 + 4], w12 = W1[o2 * 3 + 5];
    const float b10 = b1[o2], b11 = b1[o2 + 1];
    const float sc0 = g1[o2] * inv_s, sc1 = g1[o2 + 1] * inv_s;
    const float sh0 = be1[o2], sh1 = be1[o2 + 1];
    const float* sr = (const float*)(sm + OFF_SROT);
    #pragma unroll
    for (int t = 0; t < 8; ++t) {
      const int row = rbase + t * 8;
      const float x = sr[row * 3], y = sr[row * 3 + 1], z = sr[row * 3 + 2];
      const float v0 = fmaxf((x * w00 + y * w01 + z * w02 + b10) * sc0 + sh0, 0.0f);
      const float v1 = fmaxf((x * w10 + y * w11 + z * w12 + b11) * sc1 + sh1, 0.0f);
      *(unsigned*)(sm + OFF_R1 + swz(row, row * 256 + o2 * 2)) = pk_bf16(v0, v1);
    }
  }
  __syncthreads();

  // ---- L2: f2 = W2·f1ᵀ (+b2); fg = per-group colmax over s ----
  {
    f32x4 acc[2][4];
    #pragma unroll
    for (int j = 0; j < 2; ++j)
      #pragma unroll
      for (int st = 0; st < 4; ++st) acc[j][st] = (f32x4){0.f, 0.f, 0.f, 0.f};
    #pragma unroll 1
    for (int kt = 0; kt < 4; ++kt) {
      short8 bf[4];
      #pragma unroll
      for (int st = 0; st < 4; ++st) {
        const int s = st * 16 + l15;
        bf[st] = *(const short8*)(sm + OFF_R1 + swz(s, s * 256 + kt * 64 + (lq << 4)));
      }
      #pragma unroll
      for (int j = 0; j < 2; ++j) {
        const short8 wa = *(const short8*)(w2t + (((wave * 2 + j) * 4 + kt) * 64 + lane) * 8);
        #pragma unroll
        for (int st = 0; st < 4; ++st)
          acc[j][st] = __builtin_amdgcn_mfma_f32_16x16x32_bf16(wa, bf[st], acc[j][st], 0, 0, 0);
      }
    }
    #pragma unroll
    for (int j = 0; j < 2; ++j) {
      const int n0 = (wave * 2 + j) * 16 + (lq << 2);
      const f32x4 b2v = *(const f32x4*)(b2 + n0);
      float vv[4][4];
      #pragma unroll
      for (int st = 0; st < 4; ++st) {
        #pragma unroll
        for (int r = 0; r < 4; ++r) vv[st][r] = acc[j][st][r] + b2v[r];
        const int s = st * 16 + l15;
        const unsigned lo = pk_bf16(vv[st][0], vv[st][1]);
        const unsigned hi = pk_bf16(vv[st][2], vv[st][3]);
        *(u32x2*)(sm + OFF_A3 + swz(s, s * 512 + n0 * 2)) = (u32x2){lo, hi};
      }
      float fg0[4], fg1[4];
      #pragma unroll
      for (int r = 0; r < 4; ++r) {
        fg0[r] = rowmax16(fmaxf(vv[0][r], vv[1][r]));
        fg1[r] = rowmax16(fmaxf(vv[2][r], vv[3][r]));
      }
      if (l15 == 0) {
        *(u32x2*)(sm + OFF_FGA + swz(0, n0 * 2)) =
            (u32x2){pk_bf16(fg0[0], fg0[1]), pk_bf16(fg0[2], fg0[3])};
      } else if (l15 == 1) {
        *(u32x2*)(sm + OFF_FGA + swz(1, 512 + n0 * 2)) =
            (u32x2){pk_bf16(fg1[0], fg1[1]), pk_bf16(fg1[2], fg1[3])};
      }
    }
  }
  __syncthreads();

  // ---- FG: base[g][512] = W3g·fgᵀ (+b3), cols g=0,1 (cols 2-15 zero) ----
  {
    f32x4 acg[4];
    #pragma unroll
    for (int q = 0; q < 4; ++q) acg[q] = (f32x4){0.f, 0.f, 0.f, 0.f};
    #pragma unroll 1
    for (int kt = 0; kt < 8; ++kt) {
      short8 bf = (short8){0, 0, 0, 0, 0, 0, 0, 0};
      if (l15 < 2)
        bf = *(const short8*)(sm + OFF_FGA + swz(l15, l15 * 512 + kt * 64 + (lq << 4)));
      #pragma unroll
      for (int q = 0; q < 4; ++q) {
        const short8 wa = *(const short8*)(w3gt + (((wave * 4 + q) * 8 + kt) * 64 + lane) * 8);
        acg[q] = __builtin_amdgcn_mfma_f32_16x16x32_bf16(wa, bf, acg[q], 0, 0, 0);
      }
    }
    if (l15 < 2) {
      #pragma unroll
      for (int q = 0; q < 4; ++q) {
        const int n3 = (wave * 4 + q) * 16 + (lq << 2);
        const f32x4 b3v = *(const f32x4*)(b3 + n3);
        *(f32x4*)(sm + OFF_BASE + l15 * 2048 + n3 * 4) = acg[q] + b3v;
      }
    }
  }
  __syncthreads();

  // ---- L3 + L4, phased over n3-HALVES; weights read once per block. ----
  f32x4 acc4[3][4];  // L4 accumulators, live across both phases (48 VGPR)
  #pragma unroll
  for (int q = 0; q < 3; ++q)
    #pragma unroll
    for (int st = 0; st < 4; ++st) acc4[q][st] = (f32x4){0.f, 0.f, 0.f, 0.f};

  #pragma unroll 1
  for (int p = 0; p < 2; ++p) {
    // L3: f3[64 s][n3-half p] = relu(bn(base + W3f·f2ᵀ)), all 64 rows
    {
      f32x4 ac[2][4];
      #pragma unroll
      for (int jj = 0; jj < 2; ++jj)
        #pragma unroll
        for (int st = 0; st < 4; ++st) ac[jj][st] = (f32x4){0.f, 0.f, 0.f, 0.f};
      #pragma unroll 1
      for (int kt = 0; kt < 8; ++kt) {
        short8 bf[4];
        #pragma unroll
        for (int st = 0; st < 4; ++st) {
          const int s = st * 16 + l15;
          bf[st] = *(const short8*)(sm + OFF_A3 + swz(s, s * 512 + kt * 64 + (lq << 4)));
        }
        #pragma unroll
        for (int jj = 0; jj < 2; ++jj) {
          const int mt = p * 16 + wave * 2 + jj;
          const short8 wa = *(const short8*)(w3ft + ((mt * 8 + kt) * 64 + lane) * 8);
          #pragma unroll
          for (int st = 0; st < 4; ++st)
            ac[jj][st] = __builtin_amdgcn_mfma_f32_16x16x32_bf16(wa, bf[st], ac[jj][st], 0, 0, 0);
        }
      }
      #pragma unroll
      for (int jj = 0; jj < 2; ++jj) {
        const int ng = (p * 16 + wave * 2 + jj) * 16 + (lq << 2);  // global n3
        const int nl = (wave * 2 + jj) * 16 + (lq << 2);           // phase-local col
        f32x4 scv = *(const f32x4*)(g2 + ng);
        const f32x4 shv = *(const f32x4*)(be2 + ng);
        #pragma unroll
        for (int r = 0; r < 4; ++r) scv[r] *= inv_s;
        #pragma unroll
        for (int st = 0; st < 4; ++st) {
          const int g = st >> 1;
          const f32x4 bsv = *(const f32x4*)(sm + OFF_BASE + g * 2048 + ng * 4);
          float v[4];
          #pragma unroll
          for (int r = 0; r < 4; ++r)
            v[r] = fmaxf((ac[jj][st][r] + bsv[r]) * scv[r] + shv[r], 0.0f);
          const int s = st * 16 + l15;
          *(u32x2*)(sm + OFF_R1 + swz(s, s * 512 + nl * 2)) =
              (u32x2){pk_bf16(v[0], v[1]), pk_bf16(v[2], v[3])};
        }
      }
    }
    __syncthreads();
    // L4: accumulate K-half p (global kt = p*8 + ktl), all 64 rows
    #pragma unroll 1
    for (int ktl = 0; ktl < 8; ++ktl) {
      short8 bf[4];
      #pragma unroll
      for (int st = 0; st < 4; ++st) {
        const int s = st * 16 + l15;
        bf[st] = *(const short8*)(sm + OFF_R1 + swz(s, s * 512 + ktl * 64 + (lq << 4)));
      }
      #pragma unroll
      for (int q = 0; q < 3; ++q) {
        const short8 wa =
            *(const short8*)(w4t + ((((wave * 3 + q) * 16) + p * 8 + ktl) * 64 + lane) * 8);
        #pragma unroll
        for (int st = 0; st < 4; ++st)
          acc4[q][st] = __builtin_amdgcn_mfma_f32_16x16x32_bf16(wa, bf[st], acc4[q][st], 0, 0, 0);
      }
    }
    __syncthreads();
  }

  // ---- out: per-group colmax over s, +b4 ----
  #pragma unroll
  for (int q = 0; q < 3; ++q) {
    const int n4 = (wave * 3 + q) * 16 + (lq << 2);
    const f32x4 b4v = *(const f32x4*)(b4 + n4);
    float m0[4], m1[4];
    #pragma unroll
    for (int r = 0; r < 4; ++r) {
      m0[r] = rowmax16(fmaxf(acc4[q][0][r], acc4[q][1][r]));
      m1[r] = rowmax16(fmaxf(acc4[q][2][r], acc4[q][3][r]));
    }
    if (l15 == 0) {
      f32x4 o;
      #pragma unroll
      for (int r = 0; r < 4; ++r) o[r] = m0[r] + b4v[r];
      *(f32x4*)(out + (size_t)bg0 * ENC_ + n4) = o;
    } else if (l15 == 1) {
      f32x4 o;
      #pragma unroll
      for (int r = 0; r < 4; ++r) o[r] = m1[r] + b4v[r];
      *(f32x4*)(out + (size_t)(bg0 + 1) * ENC_ + n4) = o;
    }
  }
}

// ============================== launch ==============================
extern "C" void kernel_launch(void* const* d_in, const int* in_sizes, int n_in,
                              void* d_out, int out_size, void* d_ws, size_t ws_size,
                              hipStream_t stream) {
  const float* pc  = (const float*)d_in[0];
  const float* W1  = (const float*)d_in[1];
  const float* b1  = (const float*)d_in[2];
  const float* g1  = (const float*)d_in[3];
  const float* be1 = (const float*)d_in[4];
  const float* W2  = (const float*)d_in[5];
  const float* b2  = (const float*)d_in[6];
  const float* W3  = (const float*)d_in[7];
  const float* b3  = (const float*)d_in[8];
  const float* g2  = (const float*)d_in[9];
  const float* be2 = (const float*)d_in[10];
  const float* W4  = (const float*)d_in[11];
  const float* b4  = (const float*)d_in[12];
  float* out = (float*)d_out;
  char* ws = (char*)d_ws;
  int* rep    = (int*)ws;                         // 16384 B
  int* nn     = (int*)(ws + 16384);               // 524288 B
  float* rot  = (float*)(ws + 540672);            // 1572864 B
  short* w2t  = (short*)(ws + 2113536);           // 65536 B
  short* w3gt = (short*)(ws + 2179072);           // 262144 B
  short* w3ft = (short*)(ws + 2441216);           // 262144 B
  short* w4t  = (short*)(ws + 2703360);           // 393216 B (ends 3096576)

  const size_t fps_lds = 64 + (size_t)3 * N_ * 4;  // 98368 B

  convw_kernel<<<240, 256, 0, stream>>>(W2, W3, W4, w2t, w3gt, w3ft, w4t);
  fps_kernel<<<B_, 256, fps_lds, stream>>>(pc, rep);
  knn_kernel<<<B_ * G_, 256, 0, stream>>>(pc, rep, nn);
  lrf_kernel<<<B_ * G_, 64, 0, stream>>>(pc, rep, nn, rot);
  mlp_kernel<<<B_ * G_ / 2, 512, LDS_MLP, stream>>>(
      rot, W1, b1, g1, be1, b2, b3, g2, be2, b4, w2t, w3gt, w3ft, w4t, out);
}

// Round 16
// 384.147 us; speedup vs baseline: 1.0280x; 1.0067x over previous
//
#include <hip/hip_runtime.h>
#include <math.h>

#define B_ 32
#define N_ 8192
#define G_ 128
#define S_ 32
#define ENC_ 384

typedef __attribute__((ext_vector_type(8))) short short8;
typedef __attribute__((ext_vector_type(4))) float f32x4;
typedef __attribute__((ext_vector_type(2))) unsigned u32x2;

__device__ __forceinline__ unsigned short f2bf(float x) {
  unsigned u = __float_as_uint(x);
  u = u + 0x7fffu + ((u >> 16) & 1u);  // RNE
  return (unsigned short)(u >> 16);
}

// packed f32x2 -> bf16x2 (RNE), lo16 = a, hi16 = b
__device__ __forceinline__ unsigned pk_bf16(float a, float b) {
  unsigned r;
  asm("v_cvt_pk_bf16_f32 %0, %1, %2" : "=v"(r) : "v"(a), "v"(b));
  return r;
}

// DPP max step for u64 keys with row_mask; masked-off lanes get old=0 so
// max(k,0)=k (keys always < 2^63: value field is a finite positive float).
template <int CTRL, int RM>
__device__ __forceinline__ unsigned long long dpp_max_rm(unsigned long long k) {
  const int lo = (int)(unsigned)k, hi = (int)(unsigned)(k >> 32);
  const int olo = __builtin_amdgcn_update_dpp(0, lo, CTRL, RM, 0xF, true);
  const int ohi = __builtin_amdgcn_update_dpp(0, hi, CTRL, RM, 0xF, true);
  const unsigned long long o =
      ((unsigned long long)(unsigned)ohi << 32) | (unsigned)(unsigned)olo;
  return o > k ? o : k;
}

// f32 max-reduce over the 16-lane DPP row via row_ror 8/4/2/1
template <int CTRL>
__device__ __forceinline__ float dpp_fmax(float v) {
  const int x = __builtin_amdgcn_update_dpp(0, __float_as_int(v), CTRL, 0xF, 0xF, true);
  return fmaxf(v, __int_as_float(x));
}
__device__ __forceinline__ float rowmax16(float v) {
  v = dpp_fmax<0x128>(v);  // row_ror:8
  v = dpp_fmax<0x124>(v);  // row_ror:4
  v = dpp_fmax<0x122>(v);  // row_ror:2
  v = dpp_fmax<0x121>(v);  // row_ror:1
  return v;
}

// ============================== FPS ==============================
__global__ __launch_bounds__(256) void fps_kernel(const float* __restrict__ pc,
                                                  int* __restrict__ rep) {
  #pragma clang fp contract(off)
  extern __shared__ char smraw[];
  unsigned long long (*redbuf)[4] = (unsigned long long (*)[4])smraw;  // 2*4*8 B
  float* sx = (float*)(smraw + 64);
  float* sy = sx + N_;
  float* sz = sy + N_;
  const int b = blockIdx.x;
  const float* p = pc + (size_t)b * N_ * 3;
  const int tid = threadIdx.x;
  for (int i = tid; i < N_; i += 256) {
    sx[i] = p[i * 3 + 0];
    sy[i] = p[i * 3 + 1];
    sz[i] = p[i * 3 + 2];
  }
  __syncthreads();
  float X[32], Y[32], Z[32], D[32];
  #pragma unroll
  for (int j = 0; j < 32; ++j) {
    const int idx = tid + j * 256;
    X[j] = sx[idx]; Y[j] = sy[idx]; Z[j] = sz[idx];
    D[j] = INFINITY;
  }
  int last = 0;
  const int lane = tid & 63, wave = tid >> 6;  // 4 waves
  for (int k = 0; k < G_; ++k) {
    if (tid == 0) rep[b * G_ + k] = last;
    const float px = sx[last], py = sy[last], pz = sz[last];
    float bestv = -1.0f;
    int besti = 0;
    #pragma unroll
    for (int j = 0; j < 32; ++j) {
      const float dx = X[j] - px, dy = Y[j] - py, dz = Z[j] - pz;
      float dist = dx * dx;
      dist += dy * dy;
      dist += dz * dz;
      const float dj = fminf(D[j], dist);
      D[j] = dj;
      if (dj > bestv) { bestv = dj; besti = tid + j * 256; }  // ascending idx scan
    }
    // maximize (value, 8191-idx): tie -> smallest index
    unsigned long long key =
        ((unsigned long long)__float_as_uint(bestv) << 32) | (unsigned)(8191 - besti);
    key = dpp_max_rm<0xB1, 0xF>(key);   // quad_perm(1,0,3,2) = xor1
    key = dpp_max_rm<0x4E, 0xF>(key);   // quad_perm(2,3,0,1) = xor2
    key = dpp_max_rm<0x141, 0xF>(key);  // row_half_mirror = xor7
    key = dpp_max_rm<0x140, 0xF>(key);  // row_mirror = xor15 -> 16-lane groups done
    key = dpp_max_rm<0x142, 0xA>(key);  // row_bcast15 into rows 1,3
    key = dpp_max_rm<0x143, 0xC>(key);  // row_bcast31 into rows 2,3 -> row3 = wave max
    const int par = k & 1;
    if (lane == 63) redbuf[par][wave] = key;
    __syncthreads();
    unsigned long long kk = redbuf[par][0];
    #pragma unroll
    for (int w = 1; w < 4; ++w) {
      const unsigned long long o = redbuf[par][w];
      if (o > kk) kk = o;
    }
    last = 8191 - (int)(kk & 0xFFFFFFFFu);
  }
}

// ==================== LAPACK-faithful 3x3 eigh ====================
__device__ __forceinline__ double slapy2d(double x, double y) {
  return sqrt(x * x + y * y);
}

__device__ void slartg_(double f, double g, double& c, double& s, double& r) {
  if (g == 0.0) { c = 1.0; s = 0.0; r = f; }
  else if (f == 0.0) { c = 0.0; s = copysign(1.0, g); r = fabs(g); }
  else {
    const double d = sqrt(f * f + g * g);
    c = fabs(f) / d;
    r = copysign(d, f);
    s = g / r;
  }
}

__device__ void slaev2_(double a, double b, double c, double& rt1, double& rt2,
                        double& cs1, double& sn1) {
  const double sm = a + c, df = a - c;
  const double adf = fabs(df), tb = b + b, ab = fabs(tb);
  double acmx, acmn;
  if (fabs(a) > fabs(c)) { acmx = a; acmn = c; } else { acmx = c; acmn = a; }
  double rt;
  if (adf > ab) rt = adf * sqrt(1.0 + (ab / adf) * (ab / adf));
  else if (adf < ab) rt = ab * sqrt(1.0 + (adf / ab) * (adf / ab));
  else rt = ab * sqrt(2.0);
  int sgn1;
  if (sm < 0.0) { rt1 = 0.5 * (sm - rt); sgn1 = -1; rt2 = (acmx / rt1) * acmn - (b / rt1) * b; }
  else if (sm > 0.0) { rt1 = 0.5 * (sm + rt); sgn1 = 1; rt2 = (acmx / rt1) * acmn - (b / rt1) * b; }
  else { rt1 = 0.5 * rt; rt2 = -0.5 * rt; sgn1 = 1; }
  double cs;
  int sgn2;
  if (df >= 0.0) { cs = df + rt; sgn2 = 1; } else { cs = df - rt; sgn2 = -1; }
  const double acs = fabs(cs);
  if (acs > ab) {
    const double ct = -tb / cs;
    sn1 = 1.0 / sqrt(1.0 + ct * ct);
    cs1 = ct * sn1;
  } else {
    if (ab == 0.0) { cs1 = 1.0; sn1 = 0.0; }
    else {
      const double tn = -cs / tb;
      cs1 = 1.0 / sqrt(1.0 + tn * tn);
      sn1 = tn * cs1;
    }
  }
  if (sgn1 == sgn2) { const double tn = cs1; cs1 = -sn1; sn1 = tn; }
}

__device__ void eigh33_lapack(const double A[3][3], double dout[3], double Zo[3][3]) {
  double d[3], e[2];
  double Z[3][3];
  {
    const double a00 = A[0][0], a10 = A[1][0], a20 = A[2][0];
    const double a11 = A[1][1], a21 = A[2][1], a22 = A[2][2];
    if (fabs(a20) == 0.0) {
      d[0] = a00; d[1] = a11; d[2] = a22; e[0] = a10; e[1] = a21;
      Z[0][0] = 1; Z[0][1] = 0; Z[0][2] = 0;
      Z[1][0] = 0; Z[1][1] = 1; Z[1][2] = 0;
      Z[2][0] = 0; Z[2][1] = 0; Z[2][2] = 1;
    } else {
      const double beta = -copysign(slapy2d(a10, a20), a10);
      const double tau = (beta - a10) / beta;
      const double v2 = a20 / (a10 - beta);
      const double h11 = 1.0 - tau;
      const double h12 = -tau * v2;
      const double h22 = 1.0 - tau * v2 * v2;
      const double m10 = h11 * a10 + h12 * a20;
      const double m11 = h11 * a11 + h12 * a21;
      const double m12 = h11 * a21 + h12 * a22;
      const double m21 = h12 * a11 + h22 * a21;
      const double m22 = h12 * a21 + h22 * a22;
      d[0] = a00;
      d[1] = m11 * h11 + m12 * h12;
      d[2] = m21 * h12 + m22 * h22;
      e[0] = m10;
      e[1] = m21 * h11 + m22 * h12;
      Z[0][0] = 1; Z[0][1] = 0;   Z[0][2] = 0;
      Z[1][0] = 0; Z[1][1] = h11; Z[1][2] = h12;
      Z[2][0] = 0; Z[2][1] = h12; Z[2][2] = h22;
    }
  }
  const double eps = 5.9604644775390625e-08;
  const double eps2 = eps * eps;
  const double safmin = 1.1754943508222875e-38;
  int jtot = 0;
  const int nmaxit = 90;
  int l1 = 0;
  while (l1 <= 2) {
    if (l1 > 0) e[l1 - 1] = 0.0;
    int m;
    for (m = l1; m <= 1; ++m) {
      const double tst = fabs(e[m]);
      if (tst == 0.0) break;
      if (tst <= (sqrt(fabs(d[m])) * sqrt(fabs(d[m + 1]))) * eps) { e[m] = 0.0; break; }
    }
    int l = l1;
    const int lsv = l;
    int lend = m;
    const int lendsv = lend;
    l1 = m + 1;
    if (lend == l) continue;
    if (fabs(d[lend]) < fabs(d[l])) { lend = lsv; l = lendsv; }
    if (lend > l) {
      for (;;) {
        int mq;
        for (mq = l; mq <= lend - 1; ++mq) {
          const double tst = e[mq] * e[mq];
          if (tst <= (eps2 * fabs(d[mq])) * fabs(d[mq + 1]) + safmin) break;
        }
        if (mq < lend) e[mq] = 0.0;
        double p = d[l];
        if (mq == l) { d[l] = p; l = l + 1; if (l <= lend) continue; break; }
        if (mq == l + 1) {
          double rt1, rt2, c, s;
          slaev2_(d[l], e[l], d[l + 1], rt1, rt2, c, s);
          for (int i = 0; i < 3; ++i) {
            const double t1 = Z[i][l + 1], t0 = Z[i][l];
            Z[i][l + 1] = c * t1 - s * t0;
            Z[i][l] = s * t1 + c * t0;
          }
          d[l] = rt1; d[l + 1] = rt2; e[l] = 0.0;
          l += 2;
          if (l <= lend) continue;
          break;
        }
        if (jtot == nmaxit) break;
        ++jtot;
        double g = (d[l + 1] - p) / (2.0 * e[l]);
        double r = slapy2d(g, 1.0);
        g = d[mq] - p + e[l] / (g + copysign(r, g));
        double s = 1.0, c = 1.0;
        p = 0.0;
        double csv[2], ssv[2];
        for (int i = mq - 1; i >= l; --i) {
          const double f = s * e[i];
          const double bb = c * e[i];
          slartg_(g, f, c, s, r);
          if (i != mq - 1) e[i + 1] = r;
          g = d[i + 1] - p;
          r = (d[i] - g) * s + 2.0 * c * bb;
          p = s * r;
          d[i + 1] = g + p;
          g = c * r - bb;
          csv[i] = c; ssv[i] = -s;
        }
        const int mm = mq - l + 1;
        for (int j = mm - 2; j >= 0; --j) {
          const double ct = csv[l + j], st = ssv[l + j];
          for (int i = 0; i < 3; ++i) {
            const double t1 = Z[i][l + j + 1];
            Z[i][l + j + 1] = ct * t1 - st * Z[i][l + j];
            Z[i][l + j] = st * t1 + ct * Z[i][l + j];
          }
        }
        d[l] = d[l] - p;
        e[l] = g;
      }
    } else {
      for (;;) {
        int mq;
        for (mq = l; mq >= lend + 1; --mq) {
          const double tst = e[mq - 1] * e[mq - 1];
          if (tst <= (eps2 * fabs(d[mq])) * fabs(d[mq - 1]) + safmin) break;
        }
        if (mq > lend) e[mq - 1] = 0.0;
        double p = d[l];
        if (mq == l) { d[l] = p; l = l - 1; if (l >= lend) continue; break; }
        if (mq == l - 1) {
          double rt1, rt2, c, s;
          slaev2_(d[l - 1], e[l - 1], d[l], rt1, rt2, c, s);
          for (int i = 0; i < 3; ++i) {
            const double t1 = Z[i][l], t0 = Z[i][l - 1];
            Z[i][l] = c * t1 - s * t0;
            Z[i][l - 1] = s * t1 + c * t0;
          }
          d[l - 1] = rt1; d[l] = rt2; e[l - 1] = 0.0;
          l -= 2;
          if (l >= lend) continue;
          break;
        }
        if (jtot == nmaxit) break;
        ++jtot;
        double g = (d[l - 1] - p) / (2.0 * e[l - 1]);
        double r = slapy2d(g, 1.0);
        g = d[mq] - p + e[l - 1] / (g + copysign(r, g));
        double s = 1.0, c = 1.0;
        p = 0.0;
        double csv[2], ssv[2];
        for (int i = mq; i <= l - 1; ++i) {
          const double f = s * e[i];
          const double bb = c * e[i];
          slartg_(g, f, c, s, r);
          if (i != mq) e[i - 1] = r;
          g = d[i] - p;
          r = (d[i + 1] - g) * s + 2.0 * c * bb;
          p = s * r;
          d[i] = g + p;
          g = c * r - bb;
          csv[i] = c; ssv[i] = s;
        }
        const int mm = l - mq + 1;
        for (int j = 0; j <= mm - 2; ++j) {
          const double ct = csv[mq + j], st = ssv[mq + j];
          for (int i = 0; i < 3; ++i) {
            const double t1 = Z[i][mq + j + 1];
            Z[i][mq + j + 1] = ct * t1 - st * Z[i][mq + j];
            Z[i][mq + j] = st * t1 + ct * Z[i][mq + j];
          }
        }
        d[l] = d[l] - p;
        e[l - 1] = g;
      }
    }
  }
  for (int ii = 1; ii < 3; ++ii) {
    const int i = ii - 1;
    int k = i;
    double p = d[i];
    for (int j = ii; j < 3; ++j)
      if (d[j] < p) { k = j; p = d[j]; }
    if (k != i) {
      d[k] = d[i];
      d[i] = p;
      for (int q = 0; q < 3; ++q) {
        const double t = Z[q][i];
        Z[q][i] = Z[q][k];
        Z[q][k] = t;
      }
    }
  }
  dout[0] = d[0]; dout[1] = d[1]; dout[2] = d[2];
  for (int i = 0; i < 3; ++i)
    for (int j = 0; j < 3; ++j) Zo[i][j] = Z[i][j];
}

// ============================== KNN + LRF (fused) ==============================
// One block (256 thr) per (b,g). knn part identical to R15 (radix select,
// bit-identical to lax.top_k) but writes the 32 winners to LDS sidx[] instead
// of global nn. After a barrier, wave 0 runs the verbatim lrf body (center =
// qx/qy/qz already in registers). Saves the lrf kernel launch and the 512 KB
// nn global round-trip; all arithmetic order-identical to the split version.
__global__ __launch_bounds__(256) void knnlrf_kernel(const float* __restrict__ pc,
                                                     const int* __restrict__ rep,
                                                     float* __restrict__ rot) {
  #pragma clang fp contract(off)
  const int bg = blockIdx.x;
  const int b = bg >> 7;
  const float* p = pc + (size_t)b * N_ * 3;
  const int tid = threadIdx.x;
  const int lane = tid & 63, wave = tid >> 6;
  const int ridx = rep[bg];
  const float qx = p[ridx * 3 + 0], qy = p[ridx * 3 + 1], qz = p[ridx * 3 + 2];
  float nq = qx * qx;
  nq += qy * qy;
  nq += qz * qz;
  unsigned ub[32];
  #pragma unroll
  for (int j = 0; j < 32; ++j) {
    const int idx = tid + j * 256;
    const float tx = p[idx * 3 + 0], ty = p[idx * 3 + 1], tz = p[idx * 3 + 2];
    float nt = tx * tx;
    nt += ty * ty;
    nt += tz * tz;
    float dt = qx * tx;
    dt += qy * ty;
    dt += qz * tz;
    const float d2 = (nq + nt) - 2.0f * dt;
    unsigned u = __float_as_uint(d2);
    u = (u & 0x80000000u) ? ~u : (u | 0x80000000u);  // float -> sortable uint
    ub[j] = u;
  }

  __shared__ unsigned hist[4][256];
  __shared__ unsigned wsum[4];
  __shared__ int s_bin, s_cexc, s_hbin, s_cnt;
  __shared__ unsigned long long cand[128];
  __shared__ int sidx[32];

  unsigned long long curPrefix = 0;
  int need = 32;
  int prevShift = 45;
  int stopShift = 0;
  unsigned long long stopPrefix = 0;
  const int shifts[6] = {37, 29, 21, 13, 5, 0};
  #pragma unroll 1
  for (int pass = 0; pass < 6; ++pass) {
    const int sh = shifts[pass];
    const int width = prevShift - sh;
    const unsigned msk = (1u << width) - 1u;
    #pragma unroll
    for (int w = 0; w < 4; ++w) hist[w][tid] = 0;
    if (pass == 0 && tid == 0) s_cnt = 0;
    __syncthreads();
    if (sh >= 13) {  // u32 hot path: key>>x == ub>>(x-13) for x>=13
      const int shp = prevShift - 13, shd = sh - 13;
      const unsigned pref32 = (unsigned)curPrefix;
      #pragma unroll 1
      for (int j = 0; j < 32; ++j) {
        const unsigned u = ub[j];
        if ((shp >= 32 ? 0u : (u >> shp)) == pref32)
          atomicAdd(&hist[wave][(u >> shd) & msk], 1u);
      }
    } else {
      #pragma unroll 1
      for (int j = 0; j < 32; ++j) {
        const unsigned long long key =
            ((unsigned long long)ub[j] << 13) | (unsigned)(tid + j * 256);
        if ((key >> prevShift) == curPrefix)
          atomicAdd(&hist[wave][(unsigned)(key >> sh) & msk], 1u);
      }
    }
    __syncthreads();
    const unsigned v = hist[0][tid] + hist[1][tid] + hist[2][tid] + hist[3][tid];
    unsigned c = v;
    #pragma unroll
    for (int off = 1; off <= 32; off <<= 1) {
      const unsigned o = __shfl_up(c, (unsigned)off);
      if (lane >= off) c += o;
    }
    if (lane == 63) wsum[wave] = c;
    __syncthreads();
    unsigned pre = 0;
    if (wave > 0) pre += wsum[0];
    if (wave > 1) pre += wsum[1];
    if (wave > 2) pre += wsum[2];
    const unsigned cine = c + pre;
    const unsigned cexc = cine - v;
    if (cexc < (unsigned)need && (unsigned)need <= cine) {
      s_bin = tid;
      s_cexc = (int)cexc;
      s_hbin = (int)v;
    }
    __syncthreads();
    curPrefix = (curPrefix << width) | (unsigned)s_bin;
    need -= s_cexc;  // rank within selected bin
    prevShift = sh;
    // keys <= selected bin (global) = (32 - need) below-bin + hbin in-bin
    if ((32 - need) + s_hbin <= 128) {
      stopShift = sh;
      stopPrefix = curPrefix;
      break;
    }
  }
  // collect all keys with (key >> stopShift) <= stopPrefix (count <= 128)
  if (stopShift >= 13) {
    const int shd = stopShift - 13;
    const unsigned pref32 = (unsigned)stopPrefix;
    #pragma unroll 1
    for (int j = 0; j < 32; ++j) {
      if ((ub[j] >> shd) <= pref32) {
        const int pos = atomicAdd(&s_cnt, 1);
        cand[pos] = ((unsigned long long)ub[j] << 13) | (unsigned)(tid + j * 256);
      }
    }
  } else {
    #pragma unroll 1
    for (int j = 0; j < 32; ++j) {
      const unsigned long long key =
          ((unsigned long long)ub[j] << 13) | (unsigned)(tid + j * 256);
      if ((key >> stopShift) <= stopPrefix) {
        const int pos = atomicAdd(&s_cnt, 1);
        cand[pos] = key;
      }
    }
  }
  __syncthreads();
  const int cnt = s_cnt;
  if (tid < cnt) {
    const unsigned long long kt = cand[tid];
    int rank = 0;
    #pragma unroll 1
    for (int j = 0; j < cnt; ++j) rank += (cand[j] < kt) ? 1 : 0;
    if (rank < 32) sidx[rank] = (int)(kt & 8191u);
  }
  __syncthreads();

  // ---- LRF part: wave 0 only (verbatim lrf body; center = q*) ----
  if (tid < 64) {
    const int s = tid & 31;
    const int idx = sidx[s];
    const float nx = p[idx * 3 + 0] - qx;
    const float ny = p[idx * 3 + 1] - qy;
    const float nz = p[idx * 3 + 2] - qz;
    float nrm2 = nx * nx;
    nrm2 += ny * ny;
    nrm2 += nz * nz;
    const float nrm = sqrtf(nrm2);
    float wmax = nrm;
    #pragma unroll
    for (int off = 16; off >= 1; off >>= 1) wmax = fmaxf(wmax, __shfl_xor(wmax, off));
    float w = wmax - nrm;
    float wsum_ = w;
    #pragma unroll
    for (int off = 16; off >= 1; off >>= 1) wsum_ += __shfl_xor(wsum_, off);
    w = w / (wsum_ + 1e-6f);
    const float spx = 100.0f * nx, spy = 100.0f * ny, spz = 100.0f * nz;
    const float wx = w * spx, wy = w * spy, wz = w * spz;
    float c00 = wx * spx, c01 = wx * spy, c02 = wx * spz;
    float c11 = wy * spy, c12 = wy * spz, c22 = wz * spz;
    #pragma unroll
    for (int off = 16; off >= 1; off >>= 1) {
      c00 += __shfl_xor(c00, off); c01 += __shfl_xor(c01, off); c02 += __shfl_xor(c02, off);
      c11 += __shfl_xor(c11, off); c12 += __shfl_xor(c12, off); c22 += __shfl_xor(c22, off);
    }
    double A[3][3] = {{(double)c00, (double)c01, (double)c02},
                      {(double)c01, (double)c11, (double)c12},
                      {(double)c02, (double)c12, (double)c22}};
    double lam[3], Zm[3][3];
    eigh33_lapack(A, lam, Zm);
    float zx = (float)Zm[0][0], zy = (float)Zm[1][0], zz = (float)Zm[2][0];
    float xx = (float)Zm[0][2], xy = (float)Zm[1][2], xz = (float)Zm[2][2];
    float pj = zx * nx;
    pj += zy * ny;
    pj += zz * nz;
    int npos = __popcll(__ballot(pj > 0.0f) & 0xFFFFFFFFull);
    if (npos < 16) { zx = -zx; zy = -zy; zz = -zz; }
    pj = xx * nx;
    pj += xy * ny;
    pj += xz * nz;
    npos = __popcll(__ballot(pj > 0.0f) & 0xFFFFFFFFull);
    if (npos < 16) { xx = -xx; xy = -xy; xz = -xz; }
    const float yx = zy * xz - zz * xy;
    const float yy = zz * xx - zx * xz;
    const float yz = zx * xy - zy * xx;
    if (tid < 32) {
      float r0 = nx * zx; r0 += ny * zy; r0 += nz * zz;
      float r1 = nx * yx; r1 += ny * yy; r1 += nz * yz;
      float r2 = nx * xx; r2 += ny * xy; r2 += nz * xz;
      const size_t base = (size_t)(bg * S_ + s) * 3;
      rot[base + 0] = r0;
      rot[base + 1] = r1;
      rot[base + 2] = r2;
    }
  }
}

// ==================== weight pre-tiling (f32 -> bf16, MFMA-tiled) ====================
// tiled[nt][kt][lane][j] = W[nt*16 + (lane&15)][ktbase + kt*32 + (lane>>4)*8 + j]
#define P2_ 4096    // 16*4*64
#define P3_ 16384   // 32*8*64
#define P4_ 24576   // 24*16*64
__global__ __launch_bounds__(256) void convw_kernel(
    const float* __restrict__ W2, const float* __restrict__ W3,
    const float* __restrict__ W4, short* __restrict__ w2t,
    short* __restrict__ w3gt, short* __restrict__ w3ft,
    short* __restrict__ w4t) {
  int t = blockIdx.x * 256 + threadIdx.x;
  const float* src;
  short* dst;
  if (t < P2_) {
    const int lane = t & 63, kt = (t >> 6) & 3, nt = t >> 8;
    src = W2 + (nt * 16 + (lane & 15)) * 128 + kt * 32 + ((lane >> 4) << 3);
    dst = w2t + t * 8;
  } else if (t < P2_ + P3_) {
    const int p = t - P2_;
    const int lane = p & 63, kt = (p >> 6) & 7, nt = p >> 9;
    src = W3 + (nt * 16 + (lane & 15)) * 512 + kt * 32 + ((lane >> 4) << 3);
    dst = w3gt + p * 8;
  } else if (t < P2_ + 2 * P3_) {
    const int p = t - P2_ - P3_;
    const int lane = p & 63, kt = (p >> 6) & 7, nt = p >> 9;
    src = W3 + (nt * 16 + (lane & 15)) * 512 + 256 + kt * 32 + ((lane >> 4) << 3);
    dst = w3ft + p * 8;
  } else if (t < P2_ + 2 * P3_ + P4_) {
    const int p = t - P2_ - 2 * P3_;
    const int lane = p & 63, kt = (p >> 6) & 15, nt = p >> 10;
    src = W4 + (nt * 16 + (lane & 15)) * 512 + kt * 32 + ((lane >> 4) << 3);
    dst = w4t + p * 8;
  } else {
    return;
  }
  short8 v;
  #pragma unroll
  for (int j = 0; j < 8; ++j) v[j] = (short)f2bf(src[j]);
  *(short8*)dst = v;
}

// ============================== fused MFMA MLP ==============================
// One block = 512 thr (8 waves) = 2 groups (64 s rows). Operand-swapped MFMA.
// R13 n-halves phasing (weights read once, 512B f3 rows) + compacted FGA
// (2 real rows; l15>=2 feed zero B-fragments) + SROT aliasing FGA.
// LDS 69 KB -> 2 blocks/CU. kt loops `#pragma unroll 1`; no min-waves cap.
#define OFF_A3   0        // f2 [64][512B] bf16 (32768 B)
#define OFF_R1   32768    // f1 [64][256B] (16 KB) then per-phase f3 [64][512B] (32 KB)
#define OFF_FGA  65536    // fg A-tile rows 0-1 [2][512B] (1024 B); SROT aliases
#define OFF_SROT 65536    // rot [64][3] f32 (768 B) — dead before FGA written
#define OFF_BASE 66560    // base [2][512] f32 (4096 B)
#define LDS_MLP  70656    // 69 KB -> 2 blocks/CU

__device__ __forceinline__ int swz(int row, int byteoff) {
  return byteoff ^ ((row & 7) << 4);
}

__global__ __launch_bounds__(512) void mlp_kernel(
    const float* __restrict__ rot,
    const float* __restrict__ W1, const float* __restrict__ b1,
    const float* __restrict__ g1, const float* __restrict__ be1,
    const float* __restrict__ b2, const float* __restrict__ b3,
    const float* __restrict__ g2, const float* __restrict__ be2,
    const float* __restrict__ b4,
    const short* __restrict__ w2t, const short* __restrict__ w3gt,
    const short* __restrict__ w3ft, const short* __restrict__ w4t,
    float* __restrict__ out) {
  extern __shared__ char sm[];
  const int tid = threadIdx.x;
  const int lane = tid & 63, wave = tid >> 6;
  const int l15 = lane & 15, lq = lane >> 4;
  const int bg0 = blockIdx.x * 2;
  const float inv_s = 1.0f / sqrtf(1.0f + 1e-5f);

  // ---- phase 0: stage rot ----
  if (tid < 192) ((float*)(sm + OFF_SROT))[tid] = rot[(size_t)bg0 * 96 + tid];
  __syncthreads();

  // ---- L1: rot[64x3] x W1^T -> relu(bn) -> f1 [64 s][128 k] bf16 ----
  {
    const int o2 = (tid & 63) * 2;   // k pair
    const int rbase = tid >> 6;      // 0..7
    const float w00 = W1[o2 * 3], w01 = W1[o2 * 3 + 1], w02 = W1[o2 * 3 + 2];
    const float w10 = W1[o2 * 3 + 3], w11 = W1[o2 * 3 + 4], w12 = W1[o2 * 3 + 5];
    const float b10 = b1[o2], b11 = b1[o2 + 1];
    const float sc0 = g1[o2] * inv_s, sc1 = g1[o2 + 1] * inv_s;
    const float sh0 = be1[o2], sh1 = be1[o2 + 1];
    const float* sr = (const float*)(sm + OFF_SROT);
    #pragma unroll
    for (int t = 0; t < 8; ++t) {
      const int row = rbase + t * 8;
      const float x = sr[row * 3], y = sr[row * 3 + 1], z = sr[row * 3 + 2];
      const float v0 = fmaxf((x * w00 + y * w01 + z * w02 + b10) * sc0 + sh0, 0.0f);
      const float v1 = fmaxf((x * w10 + y * w11 + z * w12 + b11) * sc1 + sh1, 0.0f);
      *(unsigned*)(sm + OFF_R1 + swz(row, row * 256 + o2 * 2)) = pk_bf16(v0, v1);
    }
  }
  __syncthreads();

  // ---- L2: f2 = W2·f1ᵀ (+b2); fg = per-group colmax over s ----
  {
    f32x4 acc[2][4];
    #pragma unroll
    for (int j = 0; j < 2; ++j)
      #pragma unroll
      for (int st = 0; st < 4; ++st) acc[j][st] = (f32x4){0.f, 0.f, 0.f, 0.f};
    #pragma unroll 1
    for (int kt = 0; kt < 4; ++kt) {
      short8 bf[4];
      #pragma unroll
      for (int st = 0; st < 4; ++st) {
        const int s = st * 16 + l15;
        bf[st] = *(const short8*)(sm + OFF_R1 + swz(s, s * 256 + kt * 64 + (lq << 4)));
      }
      #pragma unroll
      for (int j = 0; j < 2; ++j) {
        const short8 wa = *(const short8*)(w2t + (((wave * 2 + j) * 4 + kt) * 64 + lane) * 8);
        #pragma unroll
        for (int st = 0; st < 4; ++st)
          acc[j][st] = __builtin_amdgcn_mfma_f32_16x16x32_bf16(wa, bf[st], acc[j][st], 0, 0, 0);
      }
    }
    #pragma unroll
    for (int j = 0; j < 2; ++j) {
      const int n0 = (wave * 2 + j) * 16 + (lq << 2);
      const f32x4 b2v = *(const f32x4*)(b2 + n0);
      float vv[4][4];
      #pragma unroll
      for (int st = 0; st < 4; ++st) {
        #pragma unroll
        for (int r = 0; r < 4; ++r) vv[st][r] = acc[j][st][r] + b2v[r];
        const int s = st * 16 + l15;
        const unsigned lo = pk_bf16(vv[st][0], vv[st][1]);
        const unsigned hi = pk_bf16(vv[st][2], vv[st][3]);
        *(u32x2*)(sm + OFF_A3 + swz(s, s * 512 + n0 * 2)) = (u32x2){lo, hi};
      }
      float fg0[4], fg1[4];
      #pragma unroll
      for (int r = 0; r < 4; ++r) {
        fg0[r] = rowmax16(fmaxf(vv[0][r], vv[1][r]));
        fg1[r] = rowmax16(fmaxf(vv[2][r], vv[3][r]));
      }
      if (l15 == 0) {
        *(u32x2*)(sm + OFF_FGA + swz(0, n0 * 2)) =
            (u32x2){pk_bf16(fg0[0], fg0[1]), pk_bf16(fg0[2], fg0[3])};
      } else if (l15 == 1) {
        *(u32x2*)(sm + OFF_FGA + swz(1, 512 + n0 * 2)) =
            (u32x2){pk_bf16(fg1[0], fg1[1]), pk_bf16(fg1[2], fg1[3])};
      }
    }
  }
  __syncthreads();

  // ---- FG: base[g][512] = W3g·fgᵀ (+b3), cols g=0,1 (cols 2-15 zero) ----
  {
    f32x4 acg[4];
    #pragma unroll
    for (int q = 0; q < 4; ++q) acg[q] = (f32x4){0.f, 0.f, 0.f, 0.f};
    #pragma unroll 1
    for (int kt = 0; kt < 8; ++kt) {
      short8 bf = (short8){0, 0, 0, 0, 0, 0, 0, 0};
      if (l15 < 2)
        bf = *(const short8*)(sm + OFF_FGA + swz(l15, l15 * 512 + kt * 64 + (lq << 4)));
      #pragma unroll
      for (int q = 0; q < 4; ++q) {
        const short8 wa = *(const short8*)(w3gt + (((wave * 4 + q) * 8 + kt) * 64 + lane) * 8);
        acg[q] = __builtin_amdgcn_mfma_f32_16x16x32_bf16(wa, bf, acg[q], 0, 0, 0);
      }
    }
    if (l15 < 2) {
      #pragma unroll
      for (int q = 0; q < 4; ++q) {
        const int n3 = (wave * 4 + q) * 16 + (lq << 2);
        const f32x4 b3v = *(const f32x4*)(b3 + n3);
        *(f32x4*)(sm + OFF_BASE + l15 * 2048 + n3 * 4) = acg[q] + b3v;
      }
    }
  }
  __syncthreads();

  // ---- L3 + L4, phased over n3-HALVES; weights read once per block. ----
  f32x4 acc4[3][4];  // L4 accumulators, live across both phases (48 VGPR)
  #pragma unroll
  for (int q = 0; q < 3; ++q)
    #pragma unroll
    for (int st = 0; st < 4; ++st) acc4[q][st] = (f32x4){0.f, 0.f, 0.f, 0.f};

  #pragma unroll 1
  for (int p = 0; p < 2; ++p) {
    // L3: f3[64 s][n3-half p] = relu(bn(base + W3f·f2ᵀ)), all 64 rows
    {
      f32x4 ac[2][4];
      #pragma unroll
      for (int jj = 0; jj < 2; ++jj)
        #pragma unroll
        for (int st = 0; st < 4; ++st) ac[jj][st] = (f32x4){0.f, 0.f, 0.f, 0.f};
      #pragma unroll 1
      for (int kt = 0; kt < 8; ++kt) {
        short8 bf[4];
        #pragma unroll
        for (int st = 0; st < 4; ++st) {
          const int s = st * 16 + l15;
          bf[st] = *(const short8*)(sm + OFF_A3 + swz(s, s * 512 + kt * 64 + (lq << 4)));
        }
        #pragma unroll
        for (int jj = 0; jj < 2; ++jj) {
          const int mt = p * 16 + wave * 2 + jj;
          const short8 wa = *(const short8*)(w3ft + ((mt * 8 + kt) * 64 + lane) * 8);
          #pragma unroll
          for (int st = 0; st < 4; ++st)
            ac[jj][st] = __builtin_amdgcn_mfma_f32_16x16x32_bf16(wa, bf[st], ac[jj][st], 0, 0, 0);
        }
      }
      #pragma unroll
      for (int jj = 0; jj < 2; ++jj) {
        const int ng = (p * 16 + wave * 2 + jj) * 16 + (lq << 2);  // global n3
        const int nl = (wave * 2 + jj) * 16 + (lq << 2);           // phase-local col
        f32x4 scv = *(const f32x4*)(g2 + ng);
        const f32x4 shv = *(const f32x4*)(be2 + ng);
        #pragma unroll
        for (int r = 0; r < 4; ++r) scv[r] *= inv_s;
        #pragma unroll
        for (int st = 0; st < 4; ++st) {
          const int g = st >> 1;
          const f32x4 bsv = *(const f32x4*)(sm + OFF_BASE + g * 2048 + ng * 4);
          float v[4];
          #pragma unroll
          for (int r = 0; r < 4; ++r)
            v[r] = fmaxf((ac[jj][st][r] + bsv[r]) * scv[r] + shv[r], 0.0f);
          const int s = st * 16 + l15;
          *(u32x2*)(sm + OFF_R1 + swz(s, s * 512 + nl * 2)) =
              (u32x2){pk_bf16(v[0], v[1]), pk_bf16(v[2], v[3])};
        }
      }
    }
    __syncthreads();
    // L4: accumulate K-half p (global kt = p*8 + ktl), all 64 rows
    #pragma unroll 1
    for (int ktl = 0; ktl < 8; ++ktl) {
      short8 bf[4];
      #pragma unroll
      for (int st = 0; st < 4; ++st) {
        const int s = st * 16 + l15;
        bf[st] = *(const short8*)(sm + OFF_R1 + swz(s, s * 512 + ktl * 64 + (lq << 4)));
      }
      #pragma unroll
      for (int q = 0; q < 3; ++q) {
        const short8 wa =
            *(const short8*)(w4t + ((((wave * 3 + q) * 16) + p * 8 + ktl) * 64 + lane) * 8);
        #pragma unroll
        for (int st = 0; st < 4; ++st)
          acc4[q][st] = __builtin_amdgcn_mfma_f32_16x16x32_bf16(wa, bf[st], acc4[q][st], 0, 0, 0);
      }
    }
    __syncthreads();
  }

  // ---- out: per-group colmax over s, +b4 ----
  #pragma unroll
  for (int q = 0; q < 3; ++q) {
    const int n4 = (wave * 3 + q) * 16 + (lq << 2);
    const f32x4 b4v = *(const f32x4*)(b4 + n4);
    float m0[4], m1[4];
    #pragma unroll
    for (int r = 0; r < 4; ++r) {
      m0[r] = rowmax16(fmaxf(acc4[q][0][r], acc4[q][1][r]));
      m1[r] = rowmax16(fmaxf(acc4[q][2][r], acc4[q][3][r]));
    }
    if (l15 == 0) {
      f32x4 o;
      #pragma unroll
      for (int r = 0; r < 4; ++r) o[r] = m0[r] + b4v[r];
      *(f32x4*)(out + (size_t)bg0 * ENC_ + n4) = o;
    } else if (l15 == 1) {
      f32x4 o;
      #pragma unroll
      for (int r = 0; r < 4; ++r) o[r] = m1[r] + b4v[r];
      *(f32x4*)(out + (size_t)(bg0 + 1) * ENC_ + n4) = o;
    }
  }
}

// ============================== launch ==============================
extern "C" void kernel_launch(void* const* d_in, const int* in_sizes, int n_in,
                              void* d_out, int out_size, void* d_ws, size_t ws_size,
                              hipStream_t stream) {
  const float* pc  = (const float*)d_in[0];
  const float* W1  = (const float*)d_in[1];
  const float* b1  = (const float*)d_in[2];
  const float* g1  = (const float*)d_in[3];
  const float* be1 = (const float*)d_in[4];
  const float* W2  = (const float*)d_in[5];
  const float* b2  = (const float*)d_in[6];
  const float* W3  = (const float*)d_in[7];
  const float* b3  = (const float*)d_in[8];
  const float* g2  = (const float*)d_in[9];
  const float* be2 = (const float*)d_in[10];
  const float* W4  = (const float*)d_in[11];
  const float* b4  = (const float*)d_in[12];
  float* out = (float*)d_out;
  char* ws = (char*)d_ws;
  int* rep    = (int*)ws;                         // 16384 B
  float* rot  = (float*)(ws + 16384);             // 1572864 B
  short* w2t  = (short*)(ws + 1589248);           // 65536 B
  short* w3gt = (short*)(ws + 1654784);           // 262144 B
  short* w3ft = (short*)(ws + 1916928);           // 262144 B
  short* w4t  = (short*)(ws + 2179072);           // 393216 B (ends 2572288)

  const size_t fps_lds = 64 + (size_t)3 * N_ * 4;  // 98368 B

  convw_kernel<<<240, 256, 0, stream>>>(W2, W3, W4, w2t, w3gt, w3ft, w4t);
  fps_kernel<<<B_, 256, fps_lds, stream>>>(pc, rep);
  knnlrf_kernel<<<B_ * G_, 256, 0, stream>>>(pc, rep, rot);
  mlp_kernel<<<B_ * G_ / 2, 512, LDS_MLP, stream>>>(
      rot, W1, b1, g1, be1, b2, b3, g2, be2, b4, w2t, w3gt, w3ft, w4t, out);
}

// Round 17
// 345.949 us; speedup vs baseline: 1.1416x; 1.1104x over previous
//
#include <hip/hip_runtime.h>
#include <math.h>

#define B_ 32
#define N_ 8192
#define G_ 128
#define S_ 32
#define ENC_ 384

typedef __attribute__((ext_vector_type(8))) short short8;
typedef __attribute__((ext_vector_type(4))) float f32x4;
typedef __attribute__((ext_vector_type(2))) unsigned u32x2;

__device__ __forceinline__ unsigned short f2bf(float x) {
  unsigned u = __float_as_uint(x);
  u = u + 0x7fffu + ((u >> 16) & 1u);  // RNE
  return (unsigned short)(u >> 16);
}

// packed f32x2 -> bf16x2 (RNE), lo16 = a, hi16 = b
__device__ __forceinline__ unsigned pk_bf16(float a, float b) {
  unsigned r;
  asm("v_cvt_pk_bf16_f32 %0, %1, %2" : "=v"(r) : "v"(a), "v"(b));
  return r;
}

// DPP max step for u64 keys with row_mask; masked-off lanes get old=0 so
// max(k,0)=k (keys always < 2^63: value field is a finite positive float).
template <int CTRL, int RM>
__device__ __forceinline__ unsigned long long dpp_max_rm(unsigned long long k) {
  const int lo = (int)(unsigned)k, hi = (int)(unsigned)(k >> 32);
  const int olo = __builtin_amdgcn_update_dpp(0, lo, CTRL, RM, 0xF, true);
  const int ohi = __builtin_amdgcn_update_dpp(0, hi, CTRL, RM, 0xF, true);
  const unsigned long long o =
      ((unsigned long long)(unsigned)ohi << 32) | (unsigned)(unsigned)olo;
  return o > k ? o : k;
}

// f32 max-reduce over the 16-lane DPP row via row_ror 8/4/2/1
template <int CTRL>
__device__ __forceinline__ float dpp_fmax(float v) {
  const int x = __builtin_amdgcn_update_dpp(0, __float_as_int(v), CTRL, 0xF, 0xF, true);
  return fmaxf(v, __int_as_float(x));
}
__device__ __forceinline__ float rowmax16(float v) {
  v = dpp_fmax<0x128>(v);  // row_ror:8
  v = dpp_fmax<0x124>(v);  // row_ror:4
  v = dpp_fmax<0x122>(v);  // row_ror:2
  v = dpp_fmax<0x121>(v);  // row_ror:1
  return v;
}

// ============================== FPS ==============================
__global__ __launch_bounds__(256) void fps_kernel(const float* __restrict__ pc,
                                                  int* __restrict__ rep) {
  #pragma clang fp contract(off)
  extern __shared__ char smraw[];
  unsigned long long (*redbuf)[4] = (unsigned long long (*)[4])smraw;  // 2*4*8 B
  float* sx = (float*)(smraw + 64);
  float* sy = sx + N_;
  float* sz = sy + N_;
  const int b = blockIdx.x;
  const float* p = pc + (size_t)b * N_ * 3;
  const int tid = threadIdx.x;
  for (int i = tid; i < N_; i += 256) {
    sx[i] = p[i * 3 + 0];
    sy[i] = p[i * 3 + 1];
    sz[i] = p[i * 3 + 2];
  }
  __syncthreads();
  float X[32], Y[32], Z[32], D[32];
  #pragma unroll
  for (int j = 0; j < 32; ++j) {
    const int idx = tid + j * 256;
    X[j] = sx[idx]; Y[j] = sy[idx]; Z[j] = sz[idx];
    D[j] = INFINITY;
  }
  int last = 0;
  const int lane = tid & 63, wave = tid >> 6;  // 4 waves
  for (int k = 0; k < G_; ++k) {
    if (tid == 0) rep[b * G_ + k] = last;
    const float px = sx[last], py = sy[last], pz = sz[last];
    float bestv = -1.0f;
    int besti = 0;
    #pragma unroll
    for (int j = 0; j < 32; ++j) {
      const float dx = X[j] - px, dy = Y[j] - py, dz = Z[j] - pz;
      float dist = dx * dx;
      dist += dy * dy;
      dist += dz * dz;
      const float dj = fminf(D[j], dist);
      D[j] = dj;
      if (dj > bestv) { bestv = dj; besti = tid + j * 256; }  // ascending idx scan
    }
    // maximize (value, 8191-idx): tie -> smallest index
    unsigned long long key =
        ((unsigned long long)__float_as_uint(bestv) << 32) | (unsigned)(8191 - besti);
    key = dpp_max_rm<0xB1, 0xF>(key);   // quad_perm(1,0,3,2) = xor1
    key = dpp_max_rm<0x4E, 0xF>(key);   // quad_perm(2,3,0,1) = xor2
    key = dpp_max_rm<0x141, 0xF>(key);  // row_half_mirror = xor7
    key = dpp_max_rm<0x140, 0xF>(key);  // row_mirror = xor15 -> 16-lane groups done
    key = dpp_max_rm<0x142, 0xA>(key);  // row_bcast15 into rows 1,3
    key = dpp_max_rm<0x143, 0xC>(key);  // row_bcast31 into rows 2,3 -> row3 = wave max
    const int par = k & 1;
    if (lane == 63) redbuf[par][wave] = key;
    __syncthreads();
    unsigned long long kk = redbuf[par][0];
    #pragma unroll
    for (int w = 1; w < 4; ++w) {
      const unsigned long long o = redbuf[par][w];
      if (o > kk) kk = o;
    }
    last = 8191 - (int)(kk & 0xFFFFFFFFu);
  }
}

// ==================== LAPACK-faithful 3x3 eigh ====================
__device__ __forceinline__ double slapy2d(double x, double y) {
  return sqrt(x * x + y * y);
}

__device__ void slartg_(double f, double g, double& c, double& s, double& r) {
  if (g == 0.0) { c = 1.0; s = 0.0; r = f; }
  else if (f == 0.0) { c = 0.0; s = copysign(1.0, g); r = fabs(g); }
  else {
    const double d = sqrt(f * f + g * g);
    c = fabs(f) / d;
    r = copysign(d, f);
    s = g / r;
  }
}

__device__ void slaev2_(double a, double b, double c, double& rt1, double& rt2,
                        double& cs1, double& sn1) {
  const double sm = a + c, df = a - c;
  const double adf = fabs(df), tb = b + b, ab = fabs(tb);
  double acmx, acmn;
  if (fabs(a) > fabs(c)) { acmx = a; acmn = c; } else { acmx = c; acmn = a; }
  double rt;
  if (adf > ab) rt = adf * sqrt(1.0 + (ab / adf) * (ab / adf));
  else if (adf < ab) rt = ab * sqrt(1.0 + (adf / ab) * (adf / ab));
  else rt = ab * sqrt(2.0);
  int sgn1;
  if (sm < 0.0) { rt1 = 0.5 * (sm - rt); sgn1 = -1; rt2 = (acmx / rt1) * acmn - (b / rt1) * b; }
  else if (sm > 0.0) { rt1 = 0.5 * (sm + rt); sgn1 = 1; rt2 = (acmx / rt1) * acmn - (b / rt1) * b; }
  else { rt1 = 0.5 * rt; rt2 = -0.5 * rt; sgn1 = 1; }
  double cs;
  int sgn2;
  if (df >= 0.0) { cs = df + rt; sgn2 = 1; } else { cs = df - rt; sgn2 = -1; }
  const double acs = fabs(cs);
  if (acs > ab) {
    const double ct = -tb / cs;
    sn1 = 1.0 / sqrt(1.0 + ct * ct);
    cs1 = ct * sn1;
  } else {
    if (ab == 0.0) { cs1 = 1.0; sn1 = 0.0; }
    else {
      const double tn = -cs / tb;
      cs1 = 1.0 / sqrt(1.0 + tn * tn);
      sn1 = tn * cs1;
    }
  }
  if (sgn1 == sgn2) { const double tn = cs1; cs1 = -sn1; sn1 = tn; }
}

__device__ void eigh33_lapack(const double A[3][3], double dout[3], double Zo[3][3]) {
  double d[3], e[2];
  double Z[3][3];
  {
    const double a00 = A[0][0], a10 = A[1][0], a20 = A[2][0];
    const double a11 = A[1][1], a21 = A[2][1], a22 = A[2][2];
    if (fabs(a20) == 0.0) {
      d[0] = a00; d[1] = a11; d[2] = a22; e[0] = a10; e[1] = a21;
      Z[0][0] = 1; Z[0][1] = 0; Z[0][2] = 0;
      Z[1][0] = 0; Z[1][1] = 1; Z[1][2] = 0;
      Z[2][0] = 0; Z[2][1] = 0; Z[2][2] = 1;
    } else {
      const double beta = -copysign(slapy2d(a10, a20), a10);
      const double tau = (beta - a10) / beta;
      const double v2 = a20 / (a10 - beta);
      const double h11 = 1.0 - tau;
      const double h12 = -tau * v2;
      const double h22 = 1.0 - tau * v2 * v2;
      const double m10 = h11 * a10 + h12 * a20;
      const double m11 = h11 * a11 + h12 * a21;
      const double m12 = h11 * a21 + h12 * a22;
      const double m21 = h12 * a11 + h22 * a21;
      const double m22 = h12 * a21 + h22 * a22;
      d[0] = a00;
      d[1] = m11 * h11 + m12 * h12;
      d[2] = m21 * h12 + m22 * h22;
      e[0] = m10;
      e[1] = m21 * h11 + m22 * h12;
      Z[0][0] = 1; Z[0][1] = 0;   Z[0][2] = 0;
      Z[1][0] = 0; Z[1][1] = h11; Z[1][2] = h12;
      Z[2][0] = 0; Z[2][1] = h12; Z[2][2] = h22;
    }
  }
  const double eps = 5.9604644775390625e-08;
  const double eps2 = eps * eps;
  const double safmin = 1.1754943508222875e-38;
  int jtot = 0;
  const int nmaxit = 90;
  int l1 = 0;
  while (l1 <= 2) {
    if (l1 > 0) e[l1 - 1] = 0.0;
    int m;
    for (m = l1; m <= 1; ++m) {
      const double tst = fabs(e[m]);
      if (tst == 0.0) break;
      if (tst <= (sqrt(fabs(d[m])) * sqrt(fabs(d[m + 1]))) * eps) { e[m] = 0.0; break; }
    }
    int l = l1;
    const int lsv = l;
    int lend = m;
    const int lendsv = lend;
    l1 = m + 1;
    if (lend == l) continue;
    if (fabs(d[lend]) < fabs(d[l])) { lend = lsv; l = lendsv; }
    if (lend > l) {
      for (;;) {
        int mq;
        for (mq = l; mq <= lend - 1; ++mq) {
          const double tst = e[mq] * e[mq];
          if (tst <= (eps2 * fabs(d[mq])) * fabs(d[mq + 1]) + safmin) break;
        }
        if (mq < lend) e[mq] = 0.0;
        double p = d[l];
        if (mq == l) { d[l] = p; l = l + 1; if (l <= lend) continue; break; }
        if (mq == l + 1) {
          double rt1, rt2, c, s;
          slaev2_(d[l], e[l], d[l + 1], rt1, rt2, c, s);
          for (int i = 0; i < 3; ++i) {
            const double t1 = Z[i][l + 1], t0 = Z[i][l];
            Z[i][l + 1] = c * t1 - s * t0;
            Z[i][l] = s * t1 + c * t0;
          }
          d[l] = rt1; d[l + 1] = rt2; e[l] = 0.0;
          l += 2;
          if (l <= lend) continue;
          break;
        }
        if (jtot == nmaxit) break;
        ++jtot;
        double g = (d[l + 1] - p) / (2.0 * e[l]);
        double r = slapy2d(g, 1.0);
        g = d[mq] - p + e[l] / (g + copysign(r, g));
        double s = 1.0, c = 1.0;
        p = 0.0;
        double csv[2], ssv[2];
        for (int i = mq - 1; i >= l; --i) {
          const double f = s * e[i];
          const double bb = c * e[i];
          slartg_(g, f, c, s, r);
          if (i != mq - 1) e[i + 1] = r;
          g = d[i + 1] - p;
          r = (d[i] - g) * s + 2.0 * c * bb;
          p = s * r;
          d[i + 1] = g + p;
          g = c * r - bb;
          csv[i] = c; ssv[i] = -s;
        }
        const int mm = mq - l + 1;
        for (int j = mm - 2; j >= 0; --j) {
          const double ct = csv[l + j], st = ssv[l + j];
          for (int i = 0; i < 3; ++i) {
            const double t1 = Z[i][l + j + 1];
            Z[i][l + j + 1] = ct * t1 - st * Z[i][l + j];
            Z[i][l + j] = st * t1 + ct * Z[i][l + j];
          }
        }
        d[l] = d[l] - p;
        e[l] = g;
      }
    } else {
      for (;;) {
        int mq;
        for (mq = l; mq >= lend + 1; --mq) {
          const double tst = e[mq - 1] * e[mq - 1];
          if (tst <= (eps2 * fabs(d[mq])) * fabs(d[mq - 1]) + safmin) break;
        }
        if (mq > lend) e[mq - 1] = 0.0;
        double p = d[l];
        if (mq == l) { d[l] = p; l = l - 1; if (l >= lend) continue; break; }
        if (mq == l - 1) {
          double rt1, rt2, c, s;
          slaev2_(d[l - 1], e[l - 1], d[l], rt1, rt2, c, s);
          for (int i = 0; i < 3; ++i) {
            const double t1 = Z[i][l], t0 = Z[i][l - 1];
            Z[i][l] = c * t1 - s * t0;
            Z[i][l - 1] = s * t1 + c * t0;
          }
          d[l - 1] = rt1; d[l] = rt2; e[l - 1] = 0.0;
          l -= 2;
          if (l >= lend) continue;
          break;
        }
        if (jtot == nmaxit) break;
        ++jtot;
        double g = (d[l - 1] - p) / (2.0 * e[l - 1]);
        double r = slapy2d(g, 1.0);
        g = d[mq] - p + e[l - 1] / (g + copysign(r, g));
        double s = 1.0, c = 1.0;
        p = 0.0;
        double csv[2], ssv[2];
        for (int i = mq; i <= l - 1; ++i) {
          const double f = s * e[i];
          const double bb = c * e[i];
          slartg_(g, f, c, s, r);
          if (i != mq) e[i - 1] = r;
          g = d[i] - p;
          r = (d[i + 1] - g) * s + 2.0 * c * bb;
          p = s * r;
          d[i] = g + p;
          g = c * r - bb;
          csv[i] = c; ssv[i] = s;
        }
        const int mm = l - mq + 1;
        for (int j = 0; j <= mm - 2; ++j) {
          const double ct = csv[mq + j], st = ssv[mq + j];
          for (int i = 0; i < 3; ++i) {
            const double t1 = Z[i][mq + j + 1];
            Z[i][mq + j + 1] = ct * t1 - st * Z[i][mq + j];
            Z[i][mq + j] = st * t1 + ct * Z[i][mq + j];
          }
        }
        d[l] = d[l] - p;
        e[l - 1] = g;
      }
    }
  }
  for (int ii = 1; ii < 3; ++ii) {
    const int i = ii - 1;
    int k = i;
    double p = d[i];
    for (int j = ii; j < 3; ++j)
      if (d[j] < p) { k = j; p = d[j]; }
    if (k != i) {
      d[k] = d[i];
      d[i] = p;
      for (int q = 0; q < 3; ++q) {
        const double t = Z[q][i];
        Z[q][i] = Z[q][k];
        Z[q][k] = t;
      }
    }
  }
  dout[0] = d[0]; dout[1] = d[1]; dout[2] = d[2];
  for (int i = 0; i < 3; ++i)
    for (int j = 0; j < 3; ++j) Zo[i][j] = Z[i][j];
}

// ============================== KNN + LRF (fused) ==============================
// One block (256 thr) per (b,g). R17: histogram copies are per LANE-GROUP
// (copy = lane&15) with stride-257 padding so copy w of digit d lands in
// bank (w+d)%32. R16 counters showed pass-0 ds_atomic serialization was the
// bottleneck (Gaussian d2 funnels 8192 adds into a few bins; 64 lanes to one
// address in a single ds_atomic serialize 64-way -> 22M bank-conflict cycles).
// Now worst case = 4-way same-address x 16 parallel banks. Counts are a sum
// over copies -> selection bit-identical to lax.top_k.
#define NHC 16     // histogram copies
#define HSTR 257   // stride (pad) for bank spreading
__global__ __launch_bounds__(256) void knnlrf_kernel(const float* __restrict__ pc,
                                                     const int* __restrict__ rep,
                                                     float* __restrict__ rot) {
  #pragma clang fp contract(off)
  const int bg = blockIdx.x;
  const int b = bg >> 7;
  const float* p = pc + (size_t)b * N_ * 3;
  const int tid = threadIdx.x;
  const int lane = tid & 63, wave = tid >> 6;
  const int hcopy = lane & (NHC - 1);
  const int ridx = rep[bg];
  const float qx = p[ridx * 3 + 0], qy = p[ridx * 3 + 1], qz = p[ridx * 3 + 2];
  float nq = qx * qx;
  nq += qy * qy;
  nq += qz * qz;
  unsigned ub[32];
  #pragma unroll
  for (int j = 0; j < 32; ++j) {
    const int idx = tid + j * 256;
    const float tx = p[idx * 3 + 0], ty = p[idx * 3 + 1], tz = p[idx * 3 + 2];
    float nt = tx * tx;
    nt += ty * ty;
    nt += tz * tz;
    float dt = qx * tx;
    dt += qy * ty;
    dt += qz * tz;
    const float d2 = (nq + nt) - 2.0f * dt;
    unsigned u = __float_as_uint(d2);
    u = (u & 0x80000000u) ? ~u : (u | 0x80000000u);  // float -> sortable uint
    ub[j] = u;
  }

  __shared__ unsigned histf[NHC * HSTR];  // 16448 B
  __shared__ unsigned wsum[4];
  __shared__ int s_bin, s_cexc, s_hbin, s_cnt;
  __shared__ unsigned long long cand[128];
  __shared__ int sidx[32];

  unsigned long long curPrefix = 0;
  int need = 32;
  int prevShift = 45;
  int stopShift = 0;
  unsigned long long stopPrefix = 0;
  const int shifts[6] = {37, 29, 21, 13, 5, 0};
  #pragma unroll 1
  for (int pass = 0; pass < 6; ++pass) {
    const int sh = shifts[pass];
    const int width = prevShift - sh;
    const unsigned msk = (1u << width) - 1u;
    for (int i = tid; i < NHC * HSTR; i += 256) histf[i] = 0;
    if (pass == 0 && tid == 0) s_cnt = 0;
    __syncthreads();
    if (sh >= 13) {  // u32 hot path: key>>x == ub>>(x-13) for x>=13
      const int shp = prevShift - 13, shd = sh - 13;
      const unsigned pref32 = (unsigned)curPrefix;
      #pragma unroll 1
      for (int j = 0; j < 32; ++j) {
        const unsigned u = ub[j];
        if ((shp >= 32 ? 0u : (u >> shp)) == pref32)
          atomicAdd(&histf[hcopy * HSTR + ((u >> shd) & msk)], 1u);
      }
    } else {
      #pragma unroll 1
      for (int j = 0; j < 32; ++j) {
        const unsigned long long key =
            ((unsigned long long)ub[j] << 13) | (unsigned)(tid + j * 256);
        if ((key >> prevShift) == curPrefix)
          atomicAdd(&histf[hcopy * HSTR + ((unsigned)(key >> sh) & msk)], 1u);
      }
    }
    __syncthreads();
    unsigned v = 0;
    #pragma unroll
    for (int w = 0; w < NHC; ++w) v += histf[w * HSTR + tid];
    unsigned c = v;
    #pragma unroll
    for (int off = 1; off <= 32; off <<= 1) {
      const unsigned o = __shfl_up(c, (unsigned)off);
      if (lane >= off) c += o;
    }
    if (lane == 63) wsum[wave] = c;
    __syncthreads();
    unsigned pre = 0;
    if (wave > 0) pre += wsum[0];
    if (wave > 1) pre += wsum[1];
    if (wave > 2) pre += wsum[2];
    const unsigned cine = c + pre;
    const unsigned cexc = cine - v;
    if (cexc < (unsigned)need && (unsigned)need <= cine) {
      s_bin = tid;
      s_cexc = (int)cexc;
      s_hbin = (int)v;
    }
    __syncthreads();
    curPrefix = (curPrefix << width) | (unsigned)s_bin;
    need -= s_cexc;  // rank within selected bin
    prevShift = sh;
    // keys <= selected bin (global) = (32 - need) below-bin + hbin in-bin
    if ((32 - need) + s_hbin <= 128) {
      stopShift = sh;
      stopPrefix = curPrefix;
      break;
    }
  }
  // collect all keys with (key >> stopShift) <= stopPrefix (count <= 128)
  if (stopShift >= 13) {
    const int shd = stopShift - 13;
    const unsigned pref32 = (unsigned)stopPrefix;
    #pragma unroll 1
    for (int j = 0; j < 32; ++j) {
      if ((ub[j] >> shd) <= pref32) {
        const int pos = atomicAdd(&s_cnt, 1);
        cand[pos] = ((unsigned long long)ub[j] << 13) | (unsigned)(tid + j * 256);
      }
    }
  } else {
    #pragma unroll 1
    for (int j = 0; j < 32; ++j) {
      const unsigned long long key =
          ((unsigned long long)ub[j] << 13) | (unsigned)(tid + j * 256);
      if ((key >> stopShift) <= stopPrefix) {
        const int pos = atomicAdd(&s_cnt, 1);
        cand[pos] = key;
      }
    }
  }
  __syncthreads();
  const int cnt = s_cnt;
  if (tid < cnt) {
    const unsigned long long kt = cand[tid];
    int rank = 0;
    #pragma unroll 1
    for (int j = 0; j < cnt; ++j) rank += (cand[j] < kt) ? 1 : 0;
    if (rank < 32) sidx[rank] = (int)(kt & 8191u);
  }
  __syncthreads();

  // ---- LRF part: wave 0 only (verbatim lrf body; center = q*) ----
  if (tid < 64) {
    const int s = tid & 31;
    const int idx = sidx[s];
    const float nx = p[idx * 3 + 0] - qx;
    const float ny = p[idx * 3 + 1] - qy;
    const float nz = p[idx * 3 + 2] - qz;
    float nrm2 = nx * nx;
    nrm2 += ny * ny;
    nrm2 += nz * nz;
    const float nrm = sqrtf(nrm2);
    float wmax = nrm;
    #pragma unroll
    for (int off = 16; off >= 1; off >>= 1) wmax = fmaxf(wmax, __shfl_xor(wmax, off));
    float w = wmax - nrm;
    float wsum_ = w;
    #pragma unroll
    for (int off = 16; off >= 1; off >>= 1) wsum_ += __shfl_xor(wsum_, off);
    w = w / (wsum_ + 1e-6f);
    const float spx = 100.0f * nx, spy = 100.0f * ny, spz = 100.0f * nz;
    const float wx = w * spx, wy = w * spy, wz = w * spz;
    float c00 = wx * spx, c01 = wx * spy, c02 = wx * spz;
    float c11 = wy * spy, c12 = wy * spz, c22 = wz * spz;
    #pragma unroll
    for (int off = 16; off >= 1; off >>= 1) {
      c00 += __shfl_xor(c00, off); c01 += __shfl_xor(c01, off); c02 += __shfl_xor(c02, off);
      c11 += __shfl_xor(c11, off); c12 += __shfl_xor(c12, off); c22 += __shfl_xor(c22, off);
    }
    double A[3][3] = {{(double)c00, (double)c01, (double)c02},
                      {(double)c01, (double)c11, (double)c12},
                      {(double)c02, (double)c12, (double)c22}};
    double lam[3], Zm[3][3];
    eigh33_lapack(A, lam, Zm);
    float zx = (float)Zm[0][0], zy = (float)Zm[1][0], zz = (float)Zm[2][0];
    float xx = (float)Zm[0][2], xy = (float)Zm[1][2], xz = (float)Zm[2][2];
    float pj = zx * nx;
    pj += zy * ny;
    pj += zz * nz;
    int npos = __popcll(__ballot(pj > 0.0f) & 0xFFFFFFFFull);
    if (npos < 16) { zx = -zx; zy = -zy; zz = -zz; }
    pj = xx * nx;
    pj += xy * ny;
    pj += xz * nz;
    npos = __popcll(__ballot(pj > 0.0f) & 0xFFFFFFFFull);
    if (npos < 16) { xx = -xx; xy = -xy; xz = -xz; }
    const float yx = zy * xz - zz * xy;
    const float yy = zz * xx - zx * xz;
    const float yz = zx * xy - zy * xx;
    if (tid < 32) {
      float r0 = nx * zx; r0 += ny * zy; r0 += nz * zz;
      float r1 = nx * yx; r1 += ny * yy; r1 += nz * yz;
      float r2 = nx * xx; r2 += ny * xy; r2 += nz * xz;
      const size_t base = (size_t)(bg * S_ + s) * 3;
      rot[base + 0] = r0;
      rot[base + 1] = r1;
      rot[base + 2] = r2;
    }
  }
}

// ==================== weight pre-tiling (f32 -> bf16, MFMA-tiled) ====================
// tiled[nt][kt][lane][j] = W[nt*16 + (lane&15)][ktbase + kt*32 + (lane>>4)*8 + j]
#define P2_ 4096    // 16*4*64
#define P3_ 16384   // 32*8*64
#define P4_ 24576   // 24*16*64
__global__ __launch_bounds__(256) void convw_kernel(
    const float* __restrict__ W2, const float* __restrict__ W3,
    const float* __restrict__ W4, short* __restrict__ w2t,
    short* __restrict__ w3gt, short* __restrict__ w3ft,
    short* __restrict__ w4t) {
  int t = blockIdx.x * 256 + threadIdx.x;
  const float* src;
  short* dst;
  if (t < P2_) {
    const int lane = t & 63, kt = (t >> 6) & 3, nt = t >> 8;
    src = W2 + (nt * 16 + (lane & 15)) * 128 + kt * 32 + ((lane >> 4) << 3);
    dst = w2t + t * 8;
  } else if (t < P2_ + P3_) {
    const int p = t - P2_;
    const int lane = p & 63, kt = (p >> 6) & 7, nt = p >> 9;
    src = W3 + (nt * 16 + (lane & 15)) * 512 + kt * 32 + ((lane >> 4) << 3);
    dst = w3gt + p * 8;
  } else if (t < P2_ + 2 * P3_) {
    const int p = t - P2_ - P3_;
    const int lane = p & 63, kt = (p >> 6) & 7, nt = p >> 9;
    src = W3 + (nt * 16 + (lane & 15)) * 512 + 256 + kt * 32 + ((lane >> 4) << 3);
    dst = w3ft + p * 8;
  } else if (t < P2_ + 2 * P3_ + P4_) {
    const int p = t - P2_ - 2 * P3_;
    const int lane = p & 63, kt = (p >> 6) & 15, nt = p >> 10;
    src = W4 + (nt * 16 + (lane & 15)) * 512 + kt * 32 + ((lane >> 4) << 3);
    dst = w4t + p * 8;
  } else {
    return;
  }
  short8 v;
  #pragma unroll
  for (int j = 0; j < 8; ++j) v[j] = (short)f2bf(src[j]);
  *(short8*)dst = v;
}

// ============================== fused MFMA MLP ==============================
// One block = 512 thr (8 waves) = 2 groups (64 s rows). Operand-swapped MFMA.
// R13 n-halves phasing (weights read once, 512B f3 rows) + compacted FGA
// (2 real rows; l15>=2 feed zero B-fragments) + SROT aliasing FGA.
// LDS 69 KB -> 2 blocks/CU. kt loops `#pragma unroll 1`; no min-waves cap.
#define OFF_A3   0        // f2 [64][512B] bf16 (32768 B)
#define OFF_R1   32768    // f1 [64][256B] (16 KB) then per-phase f3 [64][512B] (32 KB)
#define OFF_FGA  65536    // fg A-tile rows 0-1 [2][512B] (1024 B); SROT aliases
#define OFF_SROT 65536    // rot [64][3] f32 (768 B) — dead before FGA written
#define OFF_BASE 66560    // base [2][512] f32 (4096 B)
#define LDS_MLP  70656    // 69 KB -> 2 blocks/CU

__device__ __forceinline__ int swz(int row, int byteoff) {
  return byteoff ^ ((row & 7) << 4);
}

__global__ __launch_bounds__(512) void mlp_kernel(
    const float* __restrict__ rot,
    const float* __restrict__ W1, const float* __restrict__ b1,
    const float* __restrict__ g1, const float* __restrict__ be1,
    const float* __restrict__ b2, const float* __restrict__ b3,
    const float* __restrict__ g2, const float* __restrict__ be2,
    const float* __restrict__ b4,
    const short* __restrict__ w2t, const short* __restrict__ w3gt,
    const short* __restrict__ w3ft, const short* __restrict__ w4t,
    float* __restrict__ out) {
  extern __shared__ char sm[];
  const int tid = threadIdx.x;
  const int lane = tid & 63, wave = tid >> 6;
  const int l15 = lane & 15, lq = lane >> 4;
  const int bg0 = blockIdx.x * 2;
  const float inv_s = 1.0f / sqrtf(1.0f + 1e-5f);

  // ---- phase 0: stage rot ----
  if (tid < 192) ((float*)(sm + OFF_SROT))[tid] = rot[(size_t)bg0 * 96 + tid];
  __syncthreads();

  // ---- L1: rot[64x3] x W1^T -> relu(bn) -> f1 [64 s][128 k] bf16 ----
  {
    const int o2 = (tid & 63) * 2;   // k pair
    const int rbase = tid >> 6;      // 0..7
    const float w00 = W1[o2 * 3], w01 = W1[o2 * 3 + 1], w02 = W1[o2 * 3 + 2];
    const float w10 = W1[o2 * 3 + 3], w11 = W1[o2 * 3 + 4], w12 = W1[o2 * 3 + 5];
    const float b10 = b1[o2], b11 = b1[o2 + 1];
    const float sc0 = g1[o2] * inv_s, sc1 = g1[o2 + 1] * inv_s;
    const float sh0 = be1[o2], sh1 = be1[o2 + 1];
    const float* sr = (const float*)(sm + OFF_SROT);
    #pragma unroll
    for (int t = 0; t < 8; ++t) {
      const int row = rbase + t * 8;
      const float x = sr[row * 3], y = sr[row * 3 + 1], z = sr[row * 3 + 2];
      const float v0 = fmaxf((x * w00 + y * w01 + z * w02 + b10) * sc0 + sh0, 0.0f);
      const float v1 = fmaxf((x * w10 + y * w11 + z * w12 + b11) * sc1 + sh1, 0.0f);
      *(unsigned*)(sm + OFF_R1 + swz(row, row * 256 + o2 * 2)) = pk_bf16(v0, v1);
    }
  }
  __syncthreads();

  // ---- L2: f2 = W2·f1ᵀ (+b2); fg = per-group colmax over s ----
  {
    f32x4 acc[2][4];
    #pragma unroll
    for (int j = 0; j < 2; ++j)
      #pragma unroll
      for (int st = 0; st < 4; ++st) acc[j][st] = (f32x4){0.f, 0.f, 0.f, 0.f};
    #pragma unroll 1
    for (int kt = 0; kt < 4; ++kt) {
      short8 bf[4];
      #pragma unroll
      for (int st = 0; st < 4; ++st) {
        const int s = st * 16 + l15;
        bf[st] = *(const short8*)(sm + OFF_R1 + swz(s, s * 256 + kt * 64 + (lq << 4)));
      }
      #pragma unroll
      for (int j = 0; j < 2; ++j) {
        const short8 wa = *(const short8*)(w2t + (((wave * 2 + j) * 4 + kt) * 64 + lane) * 8);
        #pragma unroll
        for (int st = 0; st < 4; ++st)
          acc[j][st] = __builtin_amdgcn_mfma_f32_16x16x32_bf16(wa, bf[st], acc[j][st], 0, 0, 0);
      }
    }
    #pragma unroll
    for (int j = 0; j < 2; ++j) {
      const int n0 = (wave * 2 + j) * 16 + (lq << 2);
      const f32x4 b2v = *(const f32x4*)(b2 + n0);
      float vv[4][4];
      #pragma unroll
      for (int st = 0; st < 4; ++st) {
        #pragma unroll
        for (int r = 0; r < 4; ++r) vv[st][r] = acc[j][st][r] + b2v[r];
        const int s = st * 16 + l15;
        const unsigned lo = pk_bf16(vv[st][0], vv[st][1]);
        const unsigned hi = pk_bf16(vv[st][2], vv[st][3]);
        *(u32x2*)(sm + OFF_A3 + swz(s, s * 512 + n0 * 2)) = (u32x2){lo, hi};
      }
      float fg0[4], fg1[4];
      #pragma unroll
      for (int r = 0; r < 4; ++r) {
        fg0[r] = rowmax16(fmaxf(vv[0][r], vv[1][r]));
        fg1[r] = rowmax16(fmaxf(vv[2][r], vv[3][r]));
      }
      if (l15 == 0) {
        *(u32x2*)(sm + OFF_FGA + swz(0, n0 * 2)) =
            (u32x2){pk_bf16(fg0[0], fg0[1]), pk_bf16(fg0[2], fg0[3])};
      } else if (l15 == 1) {
        *(u32x2*)(sm + OFF_FGA + swz(1, 512 + n0 * 2)) =
            (u32x2){pk_bf16(fg1[0], fg1[1]), pk_bf16(fg1[2], fg1[3])};
      }
    }
  }
  __syncthreads();

  // ---- FG: base[g][512] = W3g·fgᵀ (+b3), cols g=0,1 (cols 2-15 zero) ----
  {
    f32x4 acg[4];
    #pragma unroll
    for (int q = 0; q < 4; ++q) acg[q] = (f32x4){0.f, 0.f, 0.f, 0.f};
    #pragma unroll 1
    for (int kt = 0; kt < 8; ++kt) {
      short8 bf = (short8){0, 0, 0, 0, 0, 0, 0, 0};
      if (l15 < 2)
        bf = *(const short8*)(sm + OFF_FGA + swz(l15, l15 * 512 + kt * 64 + (lq << 4)));
      #pragma unroll
      for (int q = 0; q < 4; ++q) {
        const short8 wa = *(const short8*)(w3gt + (((wave * 4 + q) * 8 + kt) * 64 + lane) * 8);
        acg[q] = __builtin_amdgcn_mfma_f32_16x16x32_bf16(wa, bf, acg[q], 0, 0, 0);
      }
    }
    if (l15 < 2) {
      #pragma unroll
      for (int q = 0; q < 4; ++q) {
        const int n3 = (wave * 4 + q) * 16 + (lq << 2);
        const f32x4 b3v = *(const f32x4*)(b3 + n3);
        *(f32x4*)(sm + OFF_BASE + l15 * 2048 + n3 * 4) = acg[q] + b3v;
      }
    }
  }
  __syncthreads();

  // ---- L3 + L4, phased over n3-HALVES; weights read once per block. ----
  f32x4 acc4[3][4];  // L4 accumulators, live across both phases (48 VGPR)
  #pragma unroll
  for (int q = 0; q < 3; ++q)
    #pragma unroll
    for (int st = 0; st < 4; ++st) acc4[q][st] = (f32x4){0.f, 0.f, 0.f, 0.f};

  #pragma unroll 1
  for (int p = 0; p < 2; ++p) {
    // L3: f3[64 s][n3-half p] = relu(bn(base + W3f·f2ᵀ)), all 64 rows
    {
      f32x4 ac[2][4];
      #pragma unroll
      for (int jj = 0; jj < 2; ++jj)
        #pragma unroll
        for (int st = 0; st < 4; ++st) ac[jj][st] = (f32x4){0.f, 0.f, 0.f, 0.f};
      #pragma unroll 1
      for (int kt = 0; kt < 8; ++kt) {
        short8 bf[4];
        #pragma unroll
        for (int st = 0; st < 4; ++st) {
          const int s = st * 16 + l15;
          bf[st] = *(const short8*)(sm + OFF_A3 + swz(s, s * 512 + kt * 64 + (lq << 4)));
        }
        #pragma unroll
        for (int jj = 0; jj < 2; ++jj) {
          const int mt = p * 16 + wave * 2 + jj;
          const short8 wa = *(const short8*)(w3ft + ((mt * 8 + kt) * 64 + lane) * 8);
          #pragma unroll
          for (int st = 0; st < 4; ++st)
            ac[jj][st] = __builtin_amdgcn_mfma_f32_16x16x32_bf16(wa, bf[st], ac[jj][st], 0, 0, 0);
        }
      }
      #pragma unroll
      for (int jj = 0; jj < 2; ++jj) {
        const int ng = (p * 16 + wave * 2 + jj) * 16 + (lq << 2);  // global n3
        const int nl = (wave * 2 + jj) * 16 + (lq << 2);           // phase-local col
        f32x4 scv = *(const f32x4*)(g2 + ng);
        const f32x4 shv = *(const f32x4*)(be2 + ng);
        #pragma unroll
        for (int r = 0; r < 4; ++r) scv[r] *= inv_s;
        #pragma unroll
        for (int st = 0; st < 4; ++st) {
          const int g = st >> 1;
          const f32x4 bsv = *(const f32x4*)(sm + OFF_BASE + g * 2048 + ng * 4);
          float v[4];
          #pragma unroll
          for (int r = 0; r < 4; ++r)
            v[r] = fmaxf((ac[jj][st][r] + bsv[r]) * scv[r] + shv[r], 0.0f);
          const int s = st * 16 + l15;
          *(u32x2*)(sm + OFF_R1 + swz(s, s * 512 + nl * 2)) =
              (u32x2){pk_bf16(v[0], v[1]), pk_bf16(v[2], v[3])};
        }
      }
    }
    __syncthreads();
    // L4: accumulate K-half p (global kt = p*8 + ktl), all 64 rows
    #pragma unroll 1
    for (int ktl = 0; ktl < 8; ++ktl) {
      short8 bf[4];
      #pragma unroll
      for (int st = 0; st < 4; ++st) {
        const int s = st * 16 + l15;
        bf[st] = *(const short8*)(sm + OFF_R1 + swz(s, s * 512 + ktl * 64 + (lq << 4)));
      }
      #pragma unroll
      for (int q = 0; q < 3; ++q) {
        const short8 wa =
            *(const short8*)(w4t + ((((wave * 3 + q) * 16) + p * 8 + ktl) * 64 + lane) * 8);
        #pragma unroll
        for (int st = 0; st < 4; ++st)
          acc4[q][st] = __builtin_amdgcn_mfma_f32_16x16x32_bf16(wa, bf[st], acc4[q][st], 0, 0, 0);
      }
    }
    __syncthreads();
  }

  // ---- out: per-group colmax over s, +b4 ----
  #pragma unroll
  for (int q = 0; q < 3; ++q) {
    const int n4 = (wave * 3 + q) * 16 + (lq << 2);
    const f32x4 b4v = *(const f32x4*)(b4 + n4);
    float m0[4], m1[4];
    #pragma unroll
    for (int r = 0; r < 4; ++r) {
      m0[r] = rowmax16(fmaxf(acc4[q][0][r], acc4[q][1][r]));
      m1[r] = rowmax16(fmaxf(acc4[q][2][r], acc4[q][3][r]));
    }
    if (l15 == 0) {
      f32x4 o;
      #pragma unroll
      for (int r = 0; r < 4; ++r) o[r] = m0[r] + b4v[r];
      *(f32x4*)(out + (size_t)bg0 * ENC_ + n4) = o;
    } else if (l15 == 1) {
      f32x4 o;
      #pragma unroll
      for (int r = 0; r < 4; ++r) o[r] = m1[r] + b4v[r];
      *(f32x4*)(out + (size_t)(bg0 + 1) * ENC_ + n4) = o;
    }
  }
}

// ============================== launch ==============================
extern "C" void kernel_launch(void* const* d_in, const int* in_sizes, int n_in,
                              void* d_out, int out_size, void* d_ws, size_t ws_size,
                              hipStream_t stream) {
  const float* pc  = (const float*)d_in[0];
  const float* W1  = (const float*)d_in[1];
  const float* b1  = (const float*)d_in[2];
  const float* g1  = (const float*)d_in[3];
  const float* be1 = (const float*)d_in[4];
  const float* W2  = (const float*)d_in[5];
  const float* b2  = (const float*)d_in[6];
  const float* W3  = (const float*)d_in[7];
  const float* b3  = (const float*)d_in[8];
  const float* g2  = (const float*)d_in[9];
  const float* be2 = (const float*)d_in[10];
  const float* W4  = (const float*)d_in[11];
  const float* b4  = (const float*)d_in[12];
  float* out = (float*)d_out;
  char* ws = (char*)d_ws;
  int* rep    = (int*)ws;                         // 16384 B
  float* rot  = (float*)(ws + 16384);             // 1572864 B
  short* w2t  = (short*)(ws + 1589248);           // 65536 B
  short* w3gt = (short*)(ws + 1654784);           // 262144 B
  short* w3ft = (short*)(ws + 1916928);           // 262144 B
  short* w4t  = (short*)(ws + 2179072);           // 393216 B (ends 2572288)

  const size_t fps_lds = 64 + (size_t)3 * N_ * 4;  // 98368 B

  convw_kernel<<<240, 256, 0, stream>>>(W2, W3, W4, w2t, w3gt, w3ft, w4t);
  fps_kernel<<<B_, 256, fps_lds, stream>>>(pc, rep);
  knnlrf_kernel<<<B_ * G_, 256, 0, stream>>>(pc, rep, rot);
  mlp_kernel<<<B_ * G_ / 2, 512, LDS_MLP, stream>>>(
      rot, W1, b1, g1, be1, b2, b3, g2, be2, b4, w2t, w3gt, w3ft, w4t, out);
}